// Round 4
// baseline (649.691 us; speedup 1.0000x reference)
//
#include <hip/hip_runtime.h>

#define N_NODES   100000
#define N_EDGES   1600000
#define NFEAT     128
#define NGRAPHS   2048
#define BSHIFT    5                      // 32 nodes per bucket
#define NBUCK     ((N_NODES + 31) / 32)  // 3125

typedef __attribute__((ext_vector_type(8))) short short8;   // 8 bf16 = 4 VGPRs
typedef __attribute__((ext_vector_type(4))) float f32x4;

// RNE float -> bf16 (finite inputs)
__device__ __forceinline__ unsigned short f2bf(float f) {
    unsigned int u = __float_as_uint(f);
    u += 0x7FFFu + ((u >> 16) & 1u);
    return (unsigned short)(u >> 16);
}

// ---------------- bucket histogram (LDS-aggregated) ----------------
// 128 blocks x 256 thr x 50 edges
__global__ __launch_bounds__(256) void k_bhist(const int* __restrict__ dst,
                                               int* __restrict__ bcount) {
    __shared__ int h[NBUCK];
    for (int i = threadIdx.x; i < NBUCK; i += 256) h[i] = 0;
    __syncthreads();
    int base = blockIdx.x * (256 * 50);
    #pragma unroll 1
    for (int it = 0; it < 50; ++it) {
        int e = base + it * 256 + threadIdx.x;
        if (e < N_EDGES) atomicAdd(&h[dst[e] >> BSHIFT], 1);
    }
    __syncthreads();
    for (int i = threadIdx.x; i < NBUCK; i += 256) {
        int v = h[i];
        if (v) atomicAdd(&bcount[i], v);
    }
}

// ---------------- single-block scan of bucket counts -> bstart ----------------
__global__ __launch_bounds__(1024) void k_bscan(const int* __restrict__ bcount,
                                                int* __restrict__ bstart) {
    __shared__ int s[1024];
    const int t = threadIdx.x;
    const int base = t * 4;
    int v[4]; int local = 0;
    for (int i = 0; i < 4; ++i) {
        v[i] = (base + i < NBUCK) ? bcount[base + i] : 0;
        local += v[i];
    }
    s[t] = local;
    __syncthreads();
    for (int off = 1; off < 1024; off <<= 1) {
        int x = (t >= off) ? s[t - off] : 0;
        __syncthreads();
        s[t] += x;
        __syncthreads();
    }
    int run = s[t] - local;
    for (int i = 0; i < 4; ++i) {
        if (base + i < NBUCK) bstart[base + i] = run;
        run += v[i];
    }
    if (t == 1023) bstart[NBUCK] = s[1023];
}

// ---------------- scatter edges into bucket regions ----------------
// pairs[pos] = src | (dlocal << 17); appends within a bucket share cache lines.
__global__ void k_bscatter(const int* __restrict__ src, const int* __restrict__ dst,
                           const int* __restrict__ bstart, int* __restrict__ bcur,
                           unsigned int* __restrict__ pairs) {
    int e = blockIdx.x * blockDim.x + threadIdx.x;
    if (e >= N_EDGES) return;
    int d = dst[e];
    int b = d >> BSHIFT;
    int pos = bstart[b] + atomicAdd(&bcur[b], 1);
    pairs[pos] = (unsigned int)src[e] | ((unsigned int)(d & 31) << 17);
}

// ---------------- per-bucket local sort -> csr_src, row_start, indeg, dinv ----------------
// one wave per bucket (~512 entries, 32 dst nodes)
__global__ __launch_bounds__(64) void k_csr_local(const unsigned int* __restrict__ pairs,
                                                  const int* __restrict__ bstart,
                                                  int* __restrict__ csr_src,
                                                  int* __restrict__ row_start,
                                                  int* __restrict__ indeg,
                                                  float* __restrict__ dinv) {
    __shared__ int hist[32], sstart[32], cur[32];
    const int b = blockIdx.x;
    const int l = threadIdx.x;
    const int beg = bstart[b];
    const int end = bstart[b + 1];
    if (l < 32) { hist[l] = 0; cur[l] = 0; }
    __syncthreads();
    for (int i = beg + l; i < end; i += 64)
        atomicAdd(&hist[pairs[i] >> 17], 1);
    __syncthreads();
    if (l == 0) {
        int run = 0;
        for (int j = 0; j < 32; ++j) { sstart[j] = run; run += hist[j]; }
    }
    __syncthreads();
    if (l < 32) {
        int node = b * 32 + l;
        if (node < N_NODES) {
            int cnt = hist[l];
            row_start[node] = beg + sstart[l];
            indeg[node] = cnt;
            dinv[node] = rsqrtf((float)cnt + 1.0f);
        }
    }
    __syncthreads();
    for (int i = beg + l; i < end; i += 64) {
        unsigned int v = pairs[i];
        int dl = v >> 17;
        int pos = atomicAdd(&cur[dl], 1);
        csr_src[beg + sstart[dl] + pos] = (int)(v & 0x1FFFFu);
    }
}

// ---------------- W prep: fp32 [k][n] -> bf16 transposed [n][k] ----------------
__global__ void k_prepw(const float* __restrict__ W1, const float* __restrict__ W2,
                        unsigned short* __restrict__ WT1, unsigned short* __restrict__ WT2) {
    const float* W = blockIdx.x ? W2 : W1;
    unsigned short* WT = blockIdx.x ? WT2 : WT1;
    for (int i = threadIdx.x; i < 128 * 128; i += blockDim.x) {
        int n = i >> 7, k = i & 127;
        WT[i] = f2bf(W[k * 128 + n]);
    }
}

// ---------------- MFMA GEMM: C[r,:] = bf16( (X[r,:] @ W) * dinv[r] ) ----------------
template<bool SRC_BF16>
__global__ __launch_bounds__(256) void k_gemm_mfma(const void* __restrict__ Xv,
                                                   const unsigned short* __restrict__ WT,
                                                   const float* __restrict__ dinv,
                                                   unsigned short* __restrict__ C,
                                                   int nrows) {
    __shared__ unsigned short As[128][136];
    __shared__ unsigned short Ws[128][136];
    const int tid = threadIdx.x;
    const int R0 = blockIdx.x * 128;

    {
        int r = tid >> 1;
        int h = (tid & 1) * 64;
        int gr = R0 + r;
        if (SRC_BF16) {
            const unsigned short* X = (const unsigned short*)Xv;
            for (int c = 0; c < 64; c += 8) {
                short8 v = {};
                if (gr < nrows) v = *(const short8*)(X + (size_t)gr * NFEAT + h + c);
                *(short8*)(&As[r][h + c]) = v;
            }
        } else {
            const float* X = (const float*)Xv;
            for (int c = 0; c < 64; c += 8) {
                short8 v = {};
                if (gr < nrows) {
                    float4 f0 = *(const float4*)(X + (size_t)gr * NFEAT + h + c);
                    float4 f1 = *(const float4*)(X + (size_t)gr * NFEAT + h + c + 4);
                    v[0] = (short)f2bf(f0.x); v[1] = (short)f2bf(f0.y);
                    v[2] = (short)f2bf(f0.z); v[3] = (short)f2bf(f0.w);
                    v[4] = (short)f2bf(f1.x); v[5] = (short)f2bf(f1.y);
                    v[6] = (short)f2bf(f1.z); v[7] = (short)f2bf(f1.w);
                }
                *(short8*)(&As[r][h + c]) = v;
            }
        }
    }
    {
        int n = tid >> 1;
        int h = (tid & 1) * 64;
        for (int c = 0; c < 64; c += 8)
            *(short8*)(&Ws[n][h + c]) = *(const short8*)(WT + n * 128 + h + c);
    }
    __syncthreads();

    const int wv   = tid >> 6;
    const int lane = tid & 63;
    const int m16  = lane & 15;
    const int quad = lane >> 4;

    f32x4 acc[2][8] = {};
    #pragma unroll
    for (int ks = 0; ks < 4; ++ks) {
        const int k0 = ks * 32 + quad * 8;
        short8 a0 = *(const short8*)(&As[wv * 32 + m16][k0]);
        short8 a1 = *(const short8*)(&As[wv * 32 + 16 + m16][k0]);
        short8 bb[8];
        #pragma unroll
        for (int ct = 0; ct < 8; ++ct)
            bb[ct] = *(const short8*)(&Ws[ct * 16 + m16][k0]);
        #pragma unroll
        for (int ct = 0; ct < 8; ++ct) {
            acc[0][ct] = __builtin_amdgcn_mfma_f32_16x16x32_bf16(a0, bb[ct], acc[0][ct], 0, 0, 0);
            acc[1][ct] = __builtin_amdgcn_mfma_f32_16x16x32_bf16(a1, bb[ct], acc[1][ct], 0, 0, 0);
        }
    }

    #pragma unroll
    for (int t = 0; t < 2; ++t) {
        int rbase = R0 + wv * 32 + t * 16 + quad * 4;
        #pragma unroll
        for (int reg = 0; reg < 4; ++reg) {
            int gr = rbase + reg;
            if (gr < nrows) {
                float dv = dinv[gr];
                #pragma unroll
                for (int ct = 0; ct < 8; ++ct)
                    C[(size_t)gr * NFEAT + ct * 16 + m16] = f2bf(acc[t][ct][reg] * dv);
            }
        }
    }
}

// ---------------- gather layer 1: bf16 out + relu ----------------
// wave per node; scalar (wave-uniform) CSR walk; 8-deep row unroll.
__global__ __launch_bounds__(256) void k_gather1(const unsigned short* __restrict__ xwb,
                                                 const int* __restrict__ csr_src,
                                                 const int* __restrict__ row_start,
                                                 const int* __restrict__ indeg,
                                                 const float* __restrict__ dinv,
                                                 const float* __restrict__ b,
                                                 unsigned int* __restrict__ outb) {
    long long t = (long long)blockIdx.x * blockDim.x + threadIdx.x;
    int node = __builtin_amdgcn_readfirstlane((int)(t >> 6));
    int l    = (int)(t & 63);
    if (node >= N_NODES) return;
    const unsigned int* tab = (const unsigned int*)xwb;
    const int beg = row_start[node];
    const int cnt = indeg[node];
    float ax = 0.f, ay = 0.f;
    int j = 0;
    #pragma unroll 1
    for (; j + 8 <= cnt; j += 8) {
        int s[8];
        #pragma unroll
        for (int q = 0; q < 8; ++q) s[q] = csr_src[beg + j + q];
        #pragma unroll
        for (int q = 0; q < 8; ++q) {
            unsigned int u = tab[(size_t)s[q] * 64 + l];
            ax += __uint_as_float(u << 16);
            ay += __uint_as_float(u & 0xFFFF0000u);
        }
    }
    #pragma unroll 1
    for (; j < cnt; ++j) {
        unsigned int u = tab[(size_t)csr_src[beg + j] * 64 + l];
        ax += __uint_as_float(u << 16);
        ay += __uint_as_float(u & 0xFFFF0000u);
    }
    {   // self loop
        unsigned int u = tab[(size_t)node * 64 + l];
        ax += __uint_as_float(u << 16);
        ay += __uint_as_float(u & 0xFFFF0000u);
    }
    float dv = dinv[node];
    float rx = fmaxf(ax * dv + b[l * 2], 0.f);
    float ry = fmaxf(ay * dv + b[l * 2 + 1], 0.f);
    outb[(size_t)node * 64 + l] = (unsigned int)f2bf(rx) | ((unsigned int)f2bf(ry) << 16);
}

// ---------------- gather layer 2 + fused (h2 . Wlin) + graph segment-sum ----------------
__global__ __launch_bounds__(256) void k_gather2_pool(const unsigned short* __restrict__ xwb,
                                                      const int* __restrict__ csr_src,
                                                      const int* __restrict__ row_start,
                                                      const int* __restrict__ indeg,
                                                      const float* __restrict__ dinv,
                                                      const float* __restrict__ b,
                                                      const float* __restrict__ Wlin,
                                                      const int* __restrict__ batch,
                                                      float* __restrict__ gsum) {
    long long t = (long long)blockIdx.x * blockDim.x + threadIdx.x;
    int node = __builtin_amdgcn_readfirstlane((int)(t >> 6));
    int l    = (int)(t & 63);
    if (node >= N_NODES) return;
    const unsigned int* tab = (const unsigned int*)xwb;
    const int beg = row_start[node];
    const int cnt = indeg[node];
    float ax = 0.f, ay = 0.f;
    int j = 0;
    #pragma unroll 1
    for (; j + 8 <= cnt; j += 8) {
        int s[8];
        #pragma unroll
        for (int q = 0; q < 8; ++q) s[q] = csr_src[beg + j + q];
        #pragma unroll
        for (int q = 0; q < 8; ++q) {
            unsigned int u = tab[(size_t)s[q] * 64 + l];
            ax += __uint_as_float(u << 16);
            ay += __uint_as_float(u & 0xFFFF0000u);
        }
    }
    #pragma unroll 1
    for (; j < cnt; ++j) {
        unsigned int u = tab[(size_t)csr_src[beg + j] * 64 + l];
        ax += __uint_as_float(u << 16);
        ay += __uint_as_float(u & 0xFFFF0000u);
    }
    {   // self loop
        unsigned int u = tab[(size_t)node * 64 + l];
        ax += __uint_as_float(u << 16);
        ay += __uint_as_float(u & 0xFFFF0000u);
    }
    float dv = dinv[node];
    float rx = ax * dv + b[l * 2];        // h2 feature 2l (no relu on layer 2)
    float ry = ay * dv + b[l * 2 + 1];    // h2 feature 2l+1
    float p = rx * Wlin[l * 2] + ry * Wlin[l * 2 + 1];
    for (int off = 32; off > 0; off >>= 1) p += __shfl_down(p, off);
    if (l == 0) atomicAdd(&gsum[batch[node]], p);
}

// ---------------- per-graph node count ----------------
__global__ void k_count(const int* __restrict__ batch, float* __restrict__ gcnt) {
    int i = blockIdx.x * blockDim.x + threadIdx.x;
    if (i < N_NODES) atomicAdd(&gcnt[batch[i]], 1.0f);
}

__global__ void k_final(const float* __restrict__ gsum, const float* __restrict__ gcnt,
                        const float* __restrict__ blin, float* __restrict__ out) {
    int g = blockIdx.x * blockDim.x + threadIdx.x;
    if (g < NGRAPHS) out[g] = gsum[g] / fmaxf(gcnt[g], 1.0f) + blin[0];
}

extern "C" void kernel_launch(void* const* d_in, const int* in_sizes, int n_in,
                              void* d_out, int out_size, void* d_ws, size_t ws_size,
                              hipStream_t stream) {
    const float* x    = (const float*)d_in[0];
    const int*   ei   = (const int*)d_in[1];
    const int*   bat  = (const int*)d_in[2];
    const float* W1   = (const float*)d_in[3];
    const float* b1   = (const float*)d_in[4];
    const float* W2   = (const float*)d_in[5];
    const float* b2   = (const float*)d_in[6];
    const float* Wlin = (const float*)d_in[7];
    const float* blin = (const float*)d_in[8];
    float* out = (float*)d_out;

    const int* src = ei;
    const int* dst = ei + N_EDGES;

    // ---- workspace layout ----
    const size_t NF = (size_t)N_NODES * NFEAT;
    unsigned short* bufA = (unsigned short*)d_ws;          // bf16 xw table
    unsigned short* bufB = bufA + NF;                      // bf16 h1 table
    float* dinv    = (float*)(bufB + NF);                  // [N]
    int* row_start = (int*)(dinv + N_NODES);               // [N]
    int* indeg     = row_start + N_NODES;                  // [N]
    int* bstart    = indeg + N_NODES;                      // [NBUCK+1]
    int* bcount    = bstart + NBUCK + 1;                   // [NBUCK] } zeroed
    int* bcur      = bcount + NBUCK;                       // [NBUCK] }
    float* gsum    = (float*)(bcur + NBUCK);               // [G]     }
    float* gcnt    = gsum + NGRAPHS;                       // [G]     }
    unsigned short* WT1 = (unsigned short*)(gcnt + NGRAPHS);
    unsigned short* WT2 = WT1 + 128 * 128;
    unsigned int* pairs = (unsigned int*)(WT2 + 128 * 128); // [E]
    int* csr_src  = (int*)(pairs + N_EDGES);                // [E]

    const int BS = 256;
    int node_blocks = (N_NODES + BS - 1) / BS;
    int edge_blocks = (N_EDGES + BS - 1) / BS;
    int wave_blocks = (int)(((long long)N_NODES * 64 + BS - 1) / BS);
    int gemm_blocks = (N_NODES + 127) / 128;

    // ---- zero accumulators (bcount,bcur,gsum,gcnt contiguous) ----
    hipMemsetAsync(bcount, 0, (2 * NBUCK) * sizeof(int) + (2 * NGRAPHS) * sizeof(float), stream);

    // ---- bucketed counting sort -> CSR (+ indeg, dinv, row_start) ----
    k_bhist<<<128, BS, 0, stream>>>(dst, bcount);
    k_bscan<<<1, 1024, 0, stream>>>(bcount, bstart);
    k_bscatter<<<edge_blocks, BS, 0, stream>>>(src, dst, bstart, bcur, pairs);
    k_csr_local<<<NBUCK, 64, 0, stream>>>(pairs, bstart, csr_src, row_start, indeg, dinv);
    k_prepw<<<2, BS, 0, stream>>>(W1, W2, WT1, WT2);

    // ---- layer 1 ----
    k_gemm_mfma<false><<<gemm_blocks, BS, 0, stream>>>(x, WT1, dinv, bufA, N_NODES);
    k_gather1<<<wave_blocks, BS, 0, stream>>>(bufA, csr_src, row_start, indeg, dinv, b1, (unsigned int*)bufB);

    // ---- layer 2 (+ fused pool/linear) ----
    k_gemm_mfma<true><<<gemm_blocks, BS, 0, stream>>>(bufB, WT2, dinv, bufA, N_NODES);
    k_count<<<node_blocks, BS, 0, stream>>>(bat, gcnt);
    k_gather2_pool<<<wave_blocks, BS, 0, stream>>>(bufA, csr_src, row_start, indeg, dinv, b2,
                                                   Wlin, bat, gsum);

    // ---- final ----
    k_final<<<(NGRAPHS + BS - 1) / BS, BS, 0, stream>>>(gsum, gcnt, blin, out);
}

// Round 5
// 424.306 us; speedup vs baseline: 1.5312x; 1.5312x over previous
//
#include <hip/hip_runtime.h>

#define N_NODES   100000
#define N_EDGES   1600000
#define NFEAT     128
#define NGRAPHS   2048
#define CBSHIFT   9                        // 512 nodes per coarse bucket
#define NCB       ((N_NODES + 511) / 512)  // 196
#define P1_EPB    8192                     // edges per k_p1 block

typedef __attribute__((ext_vector_type(8))) short short8;   // 8 bf16 = 4 VGPRs
typedef __attribute__((ext_vector_type(4))) float f32x4;

// RNE float -> bf16 (finite inputs)
__device__ __forceinline__ unsigned short f2bf(float f) {
    unsigned int u = __float_as_uint(f);
    u += 0x7FFFu + ((u >> 16) & 1u);
    return (unsigned short)(u >> 16);
}

// ---------------- coarse bucket histogram (LDS-aggregated) ----------------
__global__ __launch_bounds__(256) void k_bhist(const int* __restrict__ dst,
                                               int* __restrict__ bcount) {
    __shared__ int h[NCB];
    for (int i = threadIdx.x; i < NCB; i += 256) h[i] = 0;
    __syncthreads();
    int stride = gridDim.x * 256;
    for (int e = blockIdx.x * 256 + threadIdx.x; e < N_EDGES; e += stride)
        atomicAdd(&h[dst[e] >> CBSHIFT], 1);
    __syncthreads();
    for (int i = threadIdx.x; i < NCB; i += 256) {
        int v = h[i];
        if (v) atomicAdd(&bcount[i], v);
    }
}

// ---------------- scan of 196 bucket counts -> bstart, gcur ----------------
__global__ __launch_bounds__(256) void k_bscan(const int* __restrict__ bcount,
                                               int* __restrict__ bstart,
                                               int* __restrict__ gcur) {
    __shared__ int s[256];
    const int t = threadIdx.x;
    int v = (t < NCB) ? bcount[t] : 0;
    s[t] = v;
    __syncthreads();
    for (int off = 1; off < 256; off <<= 1) {
        int x = (t >= off) ? s[t - off] : 0;
        __syncthreads();
        s[t] += x;
        __syncthreads();
    }
    int excl = s[t] - v;
    if (t < NCB) { bstart[t] = excl; gcur[t] = excl; }
    if (t == 255) bstart[NCB] = s[255];
}

// ---------------- pass 1: block-ranked scatter into coarse bucket regions ----------------
// pairs[pos] = src | (dlocal << 17), dlocal in [0,512)
__global__ __launch_bounds__(256) void k_p1(const int* __restrict__ src,
                                            const int* __restrict__ dst,
                                            int* __restrict__ gcur,
                                            unsigned int* __restrict__ pairs) {
    __shared__ int hist[NCB], base[NCB], cur[NCB];
    for (int i = threadIdx.x; i < NCB; i += 256) { hist[i] = 0; cur[i] = 0; }
    __syncthreads();
    const int e0 = blockIdx.x * P1_EPB;
    const int e1 = min(e0 + P1_EPB, N_EDGES);
    for (int e = e0 + threadIdx.x; e < e1; e += 256)
        atomicAdd(&hist[dst[e] >> CBSHIFT], 1);
    __syncthreads();
    for (int i = threadIdx.x; i < NCB; i += 256) {
        int c = hist[i];
        base[i] = c ? atomicAdd(&gcur[i], c) : 0;   // one global atomic per (block,bucket)
    }
    __syncthreads();
    for (int e = e0 + threadIdx.x; e < e1; e += 256) {
        int d = dst[e];
        int b = d >> CBSHIFT;
        int r = atomicAdd(&cur[b], 1);              // LDS ranking
        pairs[base[b] + r] = (unsigned int)src[e] | ((unsigned int)(d & 511) << 17);
    }
}

// ---------------- pass 2: per-bucket sort -> csr_src, row_start, indeg, dinv ----------------
// one block per coarse bucket (~8200 entries, 512 dst nodes)
__global__ __launch_bounds__(256) void k_p2(const unsigned int* __restrict__ pairs,
                                            const int* __restrict__ bstart,
                                            int* __restrict__ csr_src,
                                            int* __restrict__ row_start,
                                            int* __restrict__ indeg,
                                            float* __restrict__ dinv) {
    __shared__ int hist[512], sst[512], cur[512], s[256];
    const int b = blockIdx.x;
    const int t = threadIdx.x;
    const int beg = bstart[b];
    const int end = bstart[b + 1];
    for (int i = t; i < 512; i += 256) { hist[i] = 0; cur[i] = 0; }
    __syncthreads();
    for (int i = beg + t; i < end; i += 256)
        atomicAdd(&hist[pairs[i] >> 17], 1);
    __syncthreads();
    // exclusive scan of 512 bins (2 bins/thread + 256-wide LDS scan)
    int a0 = hist[2 * t], a1 = hist[2 * t + 1];
    int local = a0 + a1;
    s[t] = local;
    __syncthreads();
    for (int off = 1; off < 256; off <<= 1) {
        int x = (t >= off) ? s[t - off] : 0;
        __syncthreads();
        s[t] += x;
        __syncthreads();
    }
    int excl = s[t] - local;
    sst[2 * t] = excl;
    sst[2 * t + 1] = excl + a0;
    __syncthreads();
    // per-node metadata
    for (int i = t; i < 512; i += 256) {
        int node = (b << CBSHIFT) + i;
        if (node < N_NODES) {
            int cnt = hist[i];
            row_start[node] = beg + sst[i];
            indeg[node] = cnt;
            dinv[node] = rsqrtf((float)cnt + 1.0f);
        }
    }
    __syncthreads();
    // final placement (block-local region: lines coalesce in L2)
    for (int i = beg + t; i < end; i += 256) {
        unsigned int v = pairs[i];
        int dl = v >> 17;
        int r = atomicAdd(&cur[dl], 1);
        csr_src[beg + sst[dl] + r] = (int)(v & 0x1FFFFu);
    }
}

// ---------------- W prep: fp32 [k][n] -> bf16 transposed [n][k] ----------------
__global__ void k_prepw(const float* __restrict__ W1, const float* __restrict__ W2,
                        unsigned short* __restrict__ WT1, unsigned short* __restrict__ WT2) {
    const float* W = blockIdx.x ? W2 : W1;
    unsigned short* WT = blockIdx.x ? WT2 : WT1;
    for (int i = threadIdx.x; i < 128 * 128; i += blockDim.x) {
        int n = i >> 7, k = i & 127;
        WT[i] = f2bf(W[k * 128 + n]);
    }
}

// ---------------- MFMA GEMM: C[r,:] = bf16( (X[r,:] @ W) * dinv[r] ) ----------------
template<bool SRC_BF16>
__global__ __launch_bounds__(256) void k_gemm_mfma(const void* __restrict__ Xv,
                                                   const unsigned short* __restrict__ WT,
                                                   const float* __restrict__ dinv,
                                                   unsigned short* __restrict__ C,
                                                   int nrows) {
    __shared__ unsigned short As[128][136];
    __shared__ unsigned short Ws[128][136];
    const int tid = threadIdx.x;
    const int R0 = blockIdx.x * 128;

    {
        int r = tid >> 1;
        int h = (tid & 1) * 64;
        int gr = R0 + r;
        if (SRC_BF16) {
            const unsigned short* X = (const unsigned short*)Xv;
            for (int c = 0; c < 64; c += 8) {
                short8 v = {};
                if (gr < nrows) v = *(const short8*)(X + (size_t)gr * NFEAT + h + c);
                *(short8*)(&As[r][h + c]) = v;
            }
        } else {
            const float* X = (const float*)Xv;
            for (int c = 0; c < 64; c += 8) {
                short8 v = {};
                if (gr < nrows) {
                    float4 f0 = *(const float4*)(X + (size_t)gr * NFEAT + h + c);
                    float4 f1 = *(const float4*)(X + (size_t)gr * NFEAT + h + c + 4);
                    v[0] = (short)f2bf(f0.x); v[1] = (short)f2bf(f0.y);
                    v[2] = (short)f2bf(f0.z); v[3] = (short)f2bf(f0.w);
                    v[4] = (short)f2bf(f1.x); v[5] = (short)f2bf(f1.y);
                    v[6] = (short)f2bf(f1.z); v[7] = (short)f2bf(f1.w);
                }
                *(short8*)(&As[r][h + c]) = v;
            }
        }
    }
    {
        int n = tid >> 1;
        int h = (tid & 1) * 64;
        for (int c = 0; c < 64; c += 8)
            *(short8*)(&Ws[n][h + c]) = *(const short8*)(WT + n * 128 + h + c);
    }
    __syncthreads();

    const int wv   = tid >> 6;
    const int lane = tid & 63;
    const int m16  = lane & 15;
    const int quad = lane >> 4;

    f32x4 acc[2][8] = {};
    #pragma unroll
    for (int ks = 0; ks < 4; ++ks) {
        const int k0 = ks * 32 + quad * 8;
        short8 a0 = *(const short8*)(&As[wv * 32 + m16][k0]);
        short8 a1 = *(const short8*)(&As[wv * 32 + 16 + m16][k0]);
        short8 bb[8];
        #pragma unroll
        for (int ct = 0; ct < 8; ++ct)
            bb[ct] = *(const short8*)(&Ws[ct * 16 + m16][k0]);
        #pragma unroll
        for (int ct = 0; ct < 8; ++ct) {
            acc[0][ct] = __builtin_amdgcn_mfma_f32_16x16x32_bf16(a0, bb[ct], acc[0][ct], 0, 0, 0);
            acc[1][ct] = __builtin_amdgcn_mfma_f32_16x16x32_bf16(a1, bb[ct], acc[1][ct], 0, 0, 0);
        }
    }

    #pragma unroll
    for (int t = 0; t < 2; ++t) {
        int rbase = R0 + wv * 32 + t * 16 + quad * 4;
        #pragma unroll
        for (int reg = 0; reg < 4; ++reg) {
            int gr = rbase + reg;
            if (gr < nrows) {
                float dv = dinv[gr];
                #pragma unroll
                for (int ct = 0; ct < 8; ++ct)
                    C[(size_t)gr * NFEAT + ct * 16 + m16] = f2bf(acc[t][ct][reg] * dv);
            }
        }
    }
}

// ---------------- gather layer 1: bf16 out + relu ----------------
__global__ __launch_bounds__(256) void k_gather1(const unsigned short* __restrict__ xwb,
                                                 const int* __restrict__ csr_src,
                                                 const int* __restrict__ row_start,
                                                 const int* __restrict__ indeg,
                                                 const float* __restrict__ dinv,
                                                 const float* __restrict__ b,
                                                 unsigned int* __restrict__ outb) {
    long long t = (long long)blockIdx.x * blockDim.x + threadIdx.x;
    int node = __builtin_amdgcn_readfirstlane((int)(t >> 6));
    int l    = (int)(t & 63);
    if (node >= N_NODES) return;
    const unsigned int* tab = (const unsigned int*)xwb;
    const int beg = row_start[node];
    const int cnt = indeg[node];
    float ax = 0.f, ay = 0.f;
    int j = 0;
    #pragma unroll 1
    for (; j + 8 <= cnt; j += 8) {
        int s[8];
        #pragma unroll
        for (int q = 0; q < 8; ++q) s[q] = csr_src[beg + j + q];
        #pragma unroll
        for (int q = 0; q < 8; ++q) {
            unsigned int u = tab[(size_t)s[q] * 64 + l];
            ax += __uint_as_float(u << 16);
            ay += __uint_as_float(u & 0xFFFF0000u);
        }
    }
    #pragma unroll 1
    for (; j < cnt; ++j) {
        unsigned int u = tab[(size_t)csr_src[beg + j] * 64 + l];
        ax += __uint_as_float(u << 16);
        ay += __uint_as_float(u & 0xFFFF0000u);
    }
    {   // self loop
        unsigned int u = tab[(size_t)node * 64 + l];
        ax += __uint_as_float(u << 16);
        ay += __uint_as_float(u & 0xFFFF0000u);
    }
    float dv = dinv[node];
    float rx = fmaxf(ax * dv + b[l * 2], 0.f);
    float ry = fmaxf(ay * dv + b[l * 2 + 1], 0.f);
    outb[(size_t)node * 64 + l] = (unsigned int)f2bf(rx) | ((unsigned int)f2bf(ry) << 16);
}

// ---------------- gather layer 2 + fused (h2 . Wlin) + graph segment-sum ----------------
__global__ __launch_bounds__(256) void k_gather2_pool(const unsigned short* __restrict__ xwb,
                                                      const int* __restrict__ csr_src,
                                                      const int* __restrict__ row_start,
                                                      const int* __restrict__ indeg,
                                                      const float* __restrict__ dinv,
                                                      const float* __restrict__ b,
                                                      const float* __restrict__ Wlin,
                                                      const int* __restrict__ batch,
                                                      float* __restrict__ gsum) {
    long long t = (long long)blockIdx.x * blockDim.x + threadIdx.x;
    int node = __builtin_amdgcn_readfirstlane((int)(t >> 6));
    int l    = (int)(t & 63);
    if (node >= N_NODES) return;
    const unsigned int* tab = (const unsigned int*)xwb;
    const int beg = row_start[node];
    const int cnt = indeg[node];
    float ax = 0.f, ay = 0.f;
    int j = 0;
    #pragma unroll 1
    for (; j + 8 <= cnt; j += 8) {
        int s[8];
        #pragma unroll
        for (int q = 0; q < 8; ++q) s[q] = csr_src[beg + j + q];
        #pragma unroll
        for (int q = 0; q < 8; ++q) {
            unsigned int u = tab[(size_t)s[q] * 64 + l];
            ax += __uint_as_float(u << 16);
            ay += __uint_as_float(u & 0xFFFF0000u);
        }
    }
    #pragma unroll 1
    for (; j < cnt; ++j) {
        unsigned int u = tab[(size_t)csr_src[beg + j] * 64 + l];
        ax += __uint_as_float(u << 16);
        ay += __uint_as_float(u & 0xFFFF0000u);
    }
    {   // self loop
        unsigned int u = tab[(size_t)node * 64 + l];
        ax += __uint_as_float(u << 16);
        ay += __uint_as_float(u & 0xFFFF0000u);
    }
    float dv = dinv[node];
    float rx = ax * dv + b[l * 2];
    float ry = ay * dv + b[l * 2 + 1];
    float p = rx * Wlin[l * 2] + ry * Wlin[l * 2 + 1];
    for (int off = 32; off > 0; off >>= 1) p += __shfl_down(p, off);
    if (l == 0) atomicAdd(&gsum[batch[node]], p);
}

// ---------------- per-graph node count ----------------
__global__ void k_count(const int* __restrict__ batch, float* __restrict__ gcnt) {
    int i = blockIdx.x * blockDim.x + threadIdx.x;
    if (i < N_NODES) atomicAdd(&gcnt[batch[i]], 1.0f);
}

__global__ void k_final(const float* __restrict__ gsum, const float* __restrict__ gcnt,
                        const float* __restrict__ blin, float* __restrict__ out) {
    int g = blockIdx.x * blockDim.x + threadIdx.x;
    if (g < NGRAPHS) out[g] = gsum[g] / fmaxf(gcnt[g], 1.0f) + blin[0];
}

extern "C" void kernel_launch(void* const* d_in, const int* in_sizes, int n_in,
                              void* d_out, int out_size, void* d_ws, size_t ws_size,
                              hipStream_t stream) {
    const float* x    = (const float*)d_in[0];
    const int*   ei   = (const int*)d_in[1];
    const int*   bat  = (const int*)d_in[2];
    const float* W1   = (const float*)d_in[3];
    const float* b1   = (const float*)d_in[4];
    const float* W2   = (const float*)d_in[5];
    const float* b2   = (const float*)d_in[6];
    const float* Wlin = (const float*)d_in[7];
    const float* blin = (const float*)d_in[8];
    float* out = (float*)d_out;

    const int* src = ei;
    const int* dst = ei + N_EDGES;

    // ---- workspace layout ----
    const size_t NF = (size_t)N_NODES * NFEAT;
    unsigned short* bufA = (unsigned short*)d_ws;          // bf16 xw table
    unsigned short* bufB = bufA + NF;                      // bf16 h1 table
    float* dinv    = (float*)(bufB + NF);                  // [N]
    int* row_start = (int*)(dinv + N_NODES);               // [N]
    int* indeg     = row_start + N_NODES;                  // [N]
    int* bstart    = indeg + N_NODES;                      // [NCB+1]
    int* gcur      = bstart + NCB + 1;                     // [NCB]
    int* bcount    = gcur + NCB;                           // [NCB] } zeroed
    float* gsum    = (float*)(bcount + NCB);               // [G]   }
    float* gcnt    = gsum + NGRAPHS;                       // [G]   }
    unsigned short* WT1 = (unsigned short*)(gcnt + NGRAPHS);
    unsigned short* WT2 = WT1 + 128 * 128;
    unsigned int* pairs = (unsigned int*)(WT2 + 128 * 128); // [E]
    int* csr_src  = (int*)(pairs + N_EDGES);                // [E]

    const int BS = 256;
    int node_blocks = (N_NODES + BS - 1) / BS;
    int wave_blocks = (int)(((long long)N_NODES * 64 + BS - 1) / BS);
    int gemm_blocks = (N_NODES + 127) / 128;
    int p1_blocks   = (N_EDGES + P1_EPB - 1) / P1_EPB;     // 196

    // ---- zero accumulators (bcount,gsum,gcnt contiguous) ----
    hipMemsetAsync(bcount, 0, NCB * sizeof(int) + (2 * NGRAPHS) * sizeof(float), stream);

    // ---- two-level counting sort -> CSR (+ indeg, dinv, row_start) ----
    k_bhist<<<128, BS, 0, stream>>>(dst, bcount);
    k_bscan<<<1, BS, 0, stream>>>(bcount, bstart, gcur);
    k_p1<<<p1_blocks, BS, 0, stream>>>(src, dst, gcur, pairs);
    k_p2<<<NCB, BS, 0, stream>>>(pairs, bstart, csr_src, row_start, indeg, dinv);
    k_prepw<<<2, BS, 0, stream>>>(W1, W2, WT1, WT2);

    // ---- layer 1 ----
    k_gemm_mfma<false><<<gemm_blocks, BS, 0, stream>>>(x, WT1, dinv, bufA, N_NODES);
    k_gather1<<<wave_blocks, BS, 0, stream>>>(bufA, csr_src, row_start, indeg, dinv, b1, (unsigned int*)bufB);

    // ---- layer 2 (+ fused pool/linear) ----
    k_gemm_mfma<true><<<gemm_blocks, BS, 0, stream>>>(bufB, WT2, dinv, bufA, N_NODES);
    k_count<<<node_blocks, BS, 0, stream>>>(bat, gcnt);
    k_gather2_pool<<<wave_blocks, BS, 0, stream>>>(bufA, csr_src, row_start, indeg, dinv, b2,
                                                   Wlin, bat, gsum);

    // ---- final ----
    k_final<<<(NGRAPHS + BS - 1) / BS, BS, 0, stream>>>(gsum, gcnt, blin, out);
}

// Round 6
// 411.170 us; speedup vs baseline: 1.5801x; 1.0319x over previous
//
#include <hip/hip_runtime.h>

#define N_NODES   100000
#define N_EDGES   1600000
#define NFEAT     128
#define NGRAPHS   2048
#define CBSHIFT   9                        // 512 nodes per coarse bucket
#define NCB       ((N_NODES + 511) / 512)  // 196
#define P1_EPB    8192                     // edges per k_p1 block

typedef __attribute__((ext_vector_type(8))) short short8;   // 8 bf16 = 4 VGPRs
typedef __attribute__((ext_vector_type(4))) float f32x4;

// RNE float -> bf16 (finite inputs)
__device__ __forceinline__ unsigned short f2bf(float f) {
    unsigned int u = __float_as_uint(f);
    u += 0x7FFFu + ((u >> 16) & 1u);
    return (unsigned short)(u >> 16);
}

// accumulate 8 bf16 (packed in uint4) into 8 fp32
__device__ __forceinline__ void acc8(float* acc, uint4 v) {
    acc[0] += __uint_as_float(v.x << 16);
    acc[1] += __uint_as_float(v.x & 0xFFFF0000u);
    acc[2] += __uint_as_float(v.y << 16);
    acc[3] += __uint_as_float(v.y & 0xFFFF0000u);
    acc[4] += __uint_as_float(v.z << 16);
    acc[5] += __uint_as_float(v.z & 0xFFFF0000u);
    acc[6] += __uint_as_float(v.w << 16);
    acc[7] += __uint_as_float(v.w & 0xFFFF0000u);
}

// ---------------- coarse bucket histogram (LDS-aggregated) ----------------
__global__ __launch_bounds__(256) void k_bhist(const int* __restrict__ dst,
                                               int* __restrict__ bcount) {
    __shared__ int h[NCB];
    for (int i = threadIdx.x; i < NCB; i += 256) h[i] = 0;
    __syncthreads();
    int stride = gridDim.x * 256;
    for (int e = blockIdx.x * 256 + threadIdx.x; e < N_EDGES; e += stride)
        atomicAdd(&h[dst[e] >> CBSHIFT], 1);
    __syncthreads();
    for (int i = threadIdx.x; i < NCB; i += 256) {
        int v = h[i];
        if (v) atomicAdd(&bcount[i], v);
    }
}

// ---------------- scan of 196 bucket counts -> bstart, gcur ----------------
__global__ __launch_bounds__(256) void k_bscan(const int* __restrict__ bcount,
                                               int* __restrict__ bstart,
                                               int* __restrict__ gcur) {
    __shared__ int s[256];
    const int t = threadIdx.x;
    int v = (t < NCB) ? bcount[t] : 0;
    s[t] = v;
    __syncthreads();
    for (int off = 1; off < 256; off <<= 1) {
        int x = (t >= off) ? s[t - off] : 0;
        __syncthreads();
        s[t] += x;
        __syncthreads();
    }
    int excl = s[t] - v;
    if (t < NCB) { bstart[t] = excl; gcur[t] = excl; }
    if (t == 255) bstart[NCB] = s[255];
}

// ---------------- pass 1: block-ranked scatter into coarse bucket regions ----------------
__global__ __launch_bounds__(256) void k_p1(const int* __restrict__ src,
                                            const int* __restrict__ dst,
                                            int* __restrict__ gcur,
                                            unsigned int* __restrict__ pairs) {
    __shared__ int hist[NCB], base[NCB], cur[NCB];
    for (int i = threadIdx.x; i < NCB; i += 256) { hist[i] = 0; cur[i] = 0; }
    __syncthreads();
    const int e0 = blockIdx.x * P1_EPB;
    const int e1 = min(e0 + P1_EPB, N_EDGES);
    for (int e = e0 + threadIdx.x; e < e1; e += 256)
        atomicAdd(&hist[dst[e] >> CBSHIFT], 1);
    __syncthreads();
    for (int i = threadIdx.x; i < NCB; i += 256) {
        int c = hist[i];
        base[i] = c ? atomicAdd(&gcur[i], c) : 0;
    }
    __syncthreads();
    for (int e = e0 + threadIdx.x; e < e1; e += 256) {
        int d = dst[e];
        int b = d >> CBSHIFT;
        int r = atomicAdd(&cur[b], 1);
        pairs[base[b] + r] = (unsigned int)src[e] | ((unsigned int)(d & 511) << 17);
    }
}

// ---------------- pass 2: per-bucket sort -> csr_src, row_start, indeg, dinv ----------------
__global__ __launch_bounds__(256) void k_p2(const unsigned int* __restrict__ pairs,
                                            const int* __restrict__ bstart,
                                            int* __restrict__ csr_src,
                                            int* __restrict__ row_start,
                                            int* __restrict__ indeg,
                                            float* __restrict__ dinv) {
    __shared__ int hist[512], sst[512], cur[512], s[256];
    const int b = blockIdx.x;
    const int t = threadIdx.x;
    const int beg = bstart[b];
    const int end = bstart[b + 1];
    for (int i = t; i < 512; i += 256) { hist[i] = 0; cur[i] = 0; }
    __syncthreads();
    for (int i = beg + t; i < end; i += 256)
        atomicAdd(&hist[pairs[i] >> 17], 1);
    __syncthreads();
    int a0 = hist[2 * t], a1 = hist[2 * t + 1];
    int local = a0 + a1;
    s[t] = local;
    __syncthreads();
    for (int off = 1; off < 256; off <<= 1) {
        int x = (t >= off) ? s[t - off] : 0;
        __syncthreads();
        s[t] += x;
        __syncthreads();
    }
    int excl = s[t] - local;
    sst[2 * t] = excl;
    sst[2 * t + 1] = excl + a0;
    __syncthreads();
    for (int i = t; i < 512; i += 256) {
        int node = (b << CBSHIFT) + i;
        if (node < N_NODES) {
            int cnt = hist[i];
            row_start[node] = beg + sst[i];
            indeg[node] = cnt;
            dinv[node] = rsqrtf((float)cnt + 1.0f);
        }
    }
    __syncthreads();
    for (int i = beg + t; i < end; i += 256) {
        unsigned int v = pairs[i];
        int dl = v >> 17;
        int r = atomicAdd(&cur[dl], 1);
        csr_src[beg + sst[dl] + r] = (int)(v & 0x1FFFFu);
    }
}

// ---------------- W prep: fp32 [k][n] -> bf16 transposed [n][k] ----------------
__global__ void k_prepw(const float* __restrict__ W1, const float* __restrict__ W2,
                        unsigned short* __restrict__ WT1, unsigned short* __restrict__ WT2) {
    const float* W = blockIdx.x ? W2 : W1;
    unsigned short* WT = blockIdx.x ? WT2 : WT1;
    for (int i = threadIdx.x; i < 128 * 128; i += blockDim.x) {
        int n = i >> 7, k = i & 127;
        WT[i] = f2bf(W[k * 128 + n]);
    }
}

// ---------------- MFMA GEMM: C[r,:] = bf16( (X[r,:] @ W) * dinv[r] ) ----------------
template<bool SRC_BF16>
__global__ __launch_bounds__(256) void k_gemm_mfma(const void* __restrict__ Xv,
                                                   const unsigned short* __restrict__ WT,
                                                   const float* __restrict__ dinv,
                                                   unsigned short* __restrict__ C,
                                                   int nrows) {
    __shared__ unsigned short As[128][136];
    __shared__ unsigned short Ws[128][136];
    const int tid = threadIdx.x;
    const int R0 = blockIdx.x * 128;

    {
        int r = tid >> 1;
        int h = (tid & 1) * 64;
        int gr = R0 + r;
        if (SRC_BF16) {
            const unsigned short* X = (const unsigned short*)Xv;
            for (int c = 0; c < 64; c += 8) {
                short8 v = {};
                if (gr < nrows) v = *(const short8*)(X + (size_t)gr * NFEAT + h + c);
                *(short8*)(&As[r][h + c]) = v;
            }
        } else {
            const float* X = (const float*)Xv;
            for (int c = 0; c < 64; c += 8) {
                short8 v = {};
                if (gr < nrows) {
                    float4 f0 = *(const float4*)(X + (size_t)gr * NFEAT + h + c);
                    float4 f1 = *(const float4*)(X + (size_t)gr * NFEAT + h + c + 4);
                    v[0] = (short)f2bf(f0.x); v[1] = (short)f2bf(f0.y);
                    v[2] = (short)f2bf(f0.z); v[3] = (short)f2bf(f0.w);
                    v[4] = (short)f2bf(f1.x); v[5] = (short)f2bf(f1.y);
                    v[6] = (short)f2bf(f1.z); v[7] = (short)f2bf(f1.w);
                }
                *(short8*)(&As[r][h + c]) = v;
            }
        }
    }
    {
        int n = tid >> 1;
        int h = (tid & 1) * 64;
        for (int c = 0; c < 64; c += 8)
            *(short8*)(&Ws[n][h + c]) = *(const short8*)(WT + n * 128 + h + c);
    }
    __syncthreads();

    const int wv   = tid >> 6;
    const int lane = tid & 63;
    const int m16  = lane & 15;
    const int quad = lane >> 4;

    f32x4 acc[2][8] = {};
    #pragma unroll
    for (int ks = 0; ks < 4; ++ks) {
        const int k0 = ks * 32 + quad * 8;
        short8 a0 = *(const short8*)(&As[wv * 32 + m16][k0]);
        short8 a1 = *(const short8*)(&As[wv * 32 + 16 + m16][k0]);
        short8 bb[8];
        #pragma unroll
        for (int ct = 0; ct < 8; ++ct)
            bb[ct] = *(const short8*)(&Ws[ct * 16 + m16][k0]);
        #pragma unroll
        for (int ct = 0; ct < 8; ++ct) {
            acc[0][ct] = __builtin_amdgcn_mfma_f32_16x16x32_bf16(a0, bb[ct], acc[0][ct], 0, 0, 0);
            acc[1][ct] = __builtin_amdgcn_mfma_f32_16x16x32_bf16(a1, bb[ct], acc[1][ct], 0, 0, 0);
        }
    }

    #pragma unroll
    for (int t = 0; t < 2; ++t) {
        int rbase = R0 + wv * 32 + t * 16 + quad * 4;
        #pragma unroll
        for (int reg = 0; reg < 4; ++reg) {
            int gr = rbase + reg;
            if (gr < nrows) {
                float dv = dinv[gr];
                #pragma unroll
                for (int ct = 0; ct < 8; ++ct)
                    C[(size_t)gr * NFEAT + ct * 16 + m16] = f2bf(acc[t][ct][reg] * dv);
            }
        }
    }
}

// ---------------- gather layer 1: 4 rows/wave, 16B/lane, bf16 out + relu ----------------
__global__ __launch_bounds__(256) void k_gather1(const unsigned short* __restrict__ xwb,
                                                 const int* __restrict__ csr_src,
                                                 const int* __restrict__ row_start,
                                                 const int* __restrict__ indeg,
                                                 const float* __restrict__ dinv,
                                                 const float* __restrict__ b,
                                                 uint4* __restrict__ outb) {
    long long t = (long long)blockIdx.x * blockDim.x + threadIdx.x;
    int node = __builtin_amdgcn_readfirstlane((int)(t >> 6));
    if (node >= N_NODES) return;
    const int lane = threadIdx.x & 63;
    const int g = lane >> 4;          // row group 0..3
    const int p = lane & 15;          // 16B chunk within row
    const uint4* tab = (const uint4*)xwb;   // row = 16 uint4
    const int beg = row_start[node];
    const int cnt = indeg[node];
    float acc[8] = {};
    int j = 0;
    #pragma unroll 1
    for (; j + 8 <= cnt; j += 8) {
        int s0 = csr_src[beg + j + g];
        int s1 = csr_src[beg + j + 4 + g];
        uint4 v0 = tab[(size_t)s0 * 16 + p];
        uint4 v1 = tab[(size_t)s1 * 16 + p];
        acc8(acc, v0);
        acc8(acc, v1);
    }
    #pragma unroll 1
    for (; j < cnt; j += 4) {
        int it = j + g;
        if (it < cnt) {
            uint4 v = tab[(size_t)csr_src[beg + it] * 16 + p];
            acc8(acc, v);
        }
    }
    if (g == 0) acc8(acc, tab[(size_t)node * 16 + p]);   // self loop (once)
    #pragma unroll
    for (int i = 0; i < 8; ++i) {
        acc[i] += __shfl_xor(acc[i], 16);
        acc[i] += __shfl_xor(acc[i], 32);
    }
    if (g == 0) {
        float dv = dinv[node];
        float4 b0 = *(const float4*)(b + p * 8);
        float4 b1 = *(const float4*)(b + p * 8 + 4);
        float r0 = fmaxf(acc[0] * dv + b0.x, 0.f);
        float r1 = fmaxf(acc[1] * dv + b0.y, 0.f);
        float r2 = fmaxf(acc[2] * dv + b0.z, 0.f);
        float r3 = fmaxf(acc[3] * dv + b0.w, 0.f);
        float r4 = fmaxf(acc[4] * dv + b1.x, 0.f);
        float r5 = fmaxf(acc[5] * dv + b1.y, 0.f);
        float r6 = fmaxf(acc[6] * dv + b1.z, 0.f);
        float r7 = fmaxf(acc[7] * dv + b1.w, 0.f);
        uint4 o;
        o.x = (unsigned int)f2bf(r0) | ((unsigned int)f2bf(r1) << 16);
        o.y = (unsigned int)f2bf(r2) | ((unsigned int)f2bf(r3) << 16);
        o.z = (unsigned int)f2bf(r4) | ((unsigned int)f2bf(r5) << 16);
        o.w = (unsigned int)f2bf(r6) | ((unsigned int)f2bf(r7) << 16);
        outb[(size_t)node * 16 + p] = o;
    }
}

// ---------------- gather layer 2 + fused (h2 . Wlin) + graph segment-sum ----------------
__global__ __launch_bounds__(256) void k_gather2_pool(const unsigned short* __restrict__ xwb,
                                                      const int* __restrict__ csr_src,
                                                      const int* __restrict__ row_start,
                                                      const int* __restrict__ indeg,
                                                      const float* __restrict__ dinv,
                                                      const float* __restrict__ b,
                                                      const float* __restrict__ Wlin,
                                                      const int* __restrict__ batch,
                                                      float* __restrict__ gsum) {
    long long t = (long long)blockIdx.x * blockDim.x + threadIdx.x;
    int node = __builtin_amdgcn_readfirstlane((int)(t >> 6));
    if (node >= N_NODES) return;
    const int lane = threadIdx.x & 63;
    const int g = lane >> 4;
    const int p = lane & 15;
    const uint4* tab = (const uint4*)xwb;
    const int beg = row_start[node];
    const int cnt = indeg[node];
    float acc[8] = {};
    int j = 0;
    #pragma unroll 1
    for (; j + 8 <= cnt; j += 8) {
        int s0 = csr_src[beg + j + g];
        int s1 = csr_src[beg + j + 4 + g];
        uint4 v0 = tab[(size_t)s0 * 16 + p];
        uint4 v1 = tab[(size_t)s1 * 16 + p];
        acc8(acc, v0);
        acc8(acc, v1);
    }
    #pragma unroll 1
    for (; j < cnt; j += 4) {
        int it = j + g;
        if (it < cnt) {
            uint4 v = tab[(size_t)csr_src[beg + it] * 16 + p];
            acc8(acc, v);
        }
    }
    if (g == 0) acc8(acc, tab[(size_t)node * 16 + p]);   // self loop
    #pragma unroll
    for (int i = 0; i < 8; ++i) {
        acc[i] += __shfl_xor(acc[i], 16);
        acc[i] += __shfl_xor(acc[i], 32);
    }
    // per-lane partial of (h2 . Wlin) over features p*8..p*8+7
    float dv = dinv[node];
    float4 b0 = *(const float4*)(b + p * 8);
    float4 b1 = *(const float4*)(b + p * 8 + 4);
    float4 w0 = *(const float4*)(Wlin + p * 8);
    float4 w1 = *(const float4*)(Wlin + p * 8 + 4);
    float s = (acc[0] * dv + b0.x) * w0.x + (acc[1] * dv + b0.y) * w0.y
            + (acc[2] * dv + b0.z) * w0.z + (acc[3] * dv + b0.w) * w0.w
            + (acc[4] * dv + b1.x) * w1.x + (acc[5] * dv + b1.y) * w1.y
            + (acc[6] * dv + b1.z) * w1.z + (acc[7] * dv + b1.w) * w1.w;
    s += __shfl_xor(s, 1);
    s += __shfl_xor(s, 2);
    s += __shfl_xor(s, 4);
    s += __shfl_xor(s, 8);
    if (lane == 0) atomicAdd(&gsum[batch[node]], s);
}

// ---------------- final: counts via binary search on sorted batch ----------------
__global__ void k_final(const float* __restrict__ gsum, const int* __restrict__ batch,
                        const float* __restrict__ blin, float* __restrict__ out) {
    int g = blockIdx.x * blockDim.x + threadIdx.x;
    if (g >= NGRAPHS) return;
    // lower_bound(batch, g) and lower_bound(batch, g+1)
    int lo = 0, hi = N_NODES;
    while (lo < hi) { int m = (lo + hi) >> 1; if (batch[m] < g) lo = m + 1; else hi = m; }
    int lb = lo;
    lo = 0; hi = N_NODES;
    int g1 = g + 1;
    while (lo < hi) { int m = (lo + hi) >> 1; if (batch[m] < g1) lo = m + 1; else hi = m; }
    float cnt = (float)(lo - lb);
    out[g] = gsum[g] / fmaxf(cnt, 1.0f) + blin[0];
}

extern "C" void kernel_launch(void* const* d_in, const int* in_sizes, int n_in,
                              void* d_out, int out_size, void* d_ws, size_t ws_size,
                              hipStream_t stream) {
    const float* x    = (const float*)d_in[0];
    const int*   ei   = (const int*)d_in[1];
    const int*   bat  = (const int*)d_in[2];
    const float* W1   = (const float*)d_in[3];
    const float* b1   = (const float*)d_in[4];
    const float* W2   = (const float*)d_in[5];
    const float* b2   = (const float*)d_in[6];
    const float* Wlin = (const float*)d_in[7];
    const float* blin = (const float*)d_in[8];
    float* out = (float*)d_out;

    const int* src = ei;
    const int* dst = ei + N_EDGES;

    // ---- workspace layout ----
    const size_t NF = (size_t)N_NODES * NFEAT;
    unsigned short* bufA = (unsigned short*)d_ws;          // bf16 xw table
    unsigned short* bufB = bufA + NF;                      // bf16 h1 table
    float* dinv    = (float*)(bufB + NF);                  // [N]
    int* row_start = (int*)(dinv + N_NODES);               // [N]
    int* indeg     = row_start + N_NODES;                  // [N]
    int* bstart    = indeg + N_NODES;                      // [NCB+1]
    int* gcur      = bstart + NCB + 1;                     // [NCB]
    int* bcount    = gcur + NCB;                           // [NCB] } zeroed
    float* gsum    = (float*)(bcount + NCB);               // [G]   }
    unsigned short* WT1 = (unsigned short*)(gsum + NGRAPHS);
    unsigned short* WT2 = WT1 + 128 * 128;
    unsigned int* pairs = (unsigned int*)(WT2 + 128 * 128); // [E]
    int* csr_src  = (int*)(pairs + N_EDGES);                // [E]

    const int BS = 256;
    int wave_blocks = (int)(((long long)N_NODES * 64 + BS - 1) / BS);
    int gemm_blocks = (N_NODES + 127) / 128;
    int p1_blocks   = (N_EDGES + P1_EPB - 1) / P1_EPB;     // 196

    // ---- zero accumulators (bcount,gsum contiguous) ----
    hipMemsetAsync(bcount, 0, NCB * sizeof(int) + NGRAPHS * sizeof(float), stream);

    // ---- two-level counting sort -> CSR (+ indeg, dinv, row_start) ----
    k_bhist<<<128, BS, 0, stream>>>(dst, bcount);
    k_bscan<<<1, BS, 0, stream>>>(bcount, bstart, gcur);
    k_p1<<<p1_blocks, BS, 0, stream>>>(src, dst, gcur, pairs);
    k_p2<<<NCB, BS, 0, stream>>>(pairs, bstart, csr_src, row_start, indeg, dinv);
    k_prepw<<<2, BS, 0, stream>>>(W1, W2, WT1, WT2);

    // ---- layer 1 ----
    k_gemm_mfma<false><<<gemm_blocks, BS, 0, stream>>>(x, WT1, dinv, bufA, N_NODES);
    k_gather1<<<wave_blocks, BS, 0, stream>>>(bufA, csr_src, row_start, indeg, dinv, b1, (uint4*)bufB);

    // ---- layer 2 (+ fused pool/linear) ----
    k_gemm_mfma<true><<<gemm_blocks, BS, 0, stream>>>(bufB, WT2, dinv, bufA, N_NODES);
    k_gather2_pool<<<wave_blocks, BS, 0, stream>>>(bufA, csr_src, row_start, indeg, dinv, b2,
                                                   Wlin, bat, gsum);

    // ---- final ----
    k_final<<<(NGRAPHS + BS - 1) / BS, BS, 0, stream>>>(gsum, bat, blin, out);
}

// Round 7
// 374.949 us; speedup vs baseline: 1.7327x; 1.0966x over previous
//
#include <hip/hip_runtime.h>

#define N_NODES   100000
#define N_EDGES   1600000
#define NFEAT     128
#define NGRAPHS   2048
#define CBSHIFT   9                        // 512 nodes per coarse bucket
#define NCB       ((N_NODES + 511) / 512)  // 196
#define P1_EPB    8192                     // edges per k_p1 block

typedef __attribute__((ext_vector_type(8))) short short8;   // 8 bf16 = 4 VGPRs
typedef __attribute__((ext_vector_type(4))) float f32x4;

// RNE float -> bf16 (finite inputs)
__device__ __forceinline__ unsigned short f2bf(float f) {
    unsigned int u = __float_as_uint(f);
    u += 0x7FFFu + ((u >> 16) & 1u);
    return (unsigned short)(u >> 16);
}

// accumulate 8 bf16 (packed in uint4) into 8 fp32
__device__ __forceinline__ void acc8(float* acc, uint4 v) {
    acc[0] += __uint_as_float(v.x << 16);
    acc[1] += __uint_as_float(v.x & 0xFFFF0000u);
    acc[2] += __uint_as_float(v.y << 16);
    acc[3] += __uint_as_float(v.y & 0xFFFF0000u);
    acc[4] += __uint_as_float(v.z << 16);
    acc[5] += __uint_as_float(v.z & 0xFFFF0000u);
    acc[6] += __uint_as_float(v.w << 16);
    acc[7] += __uint_as_float(v.w & 0xFFFF0000u);
}

// ---------------- coarse bucket histogram (LDS-aggregated) ----------------
__global__ __launch_bounds__(256) void k_bhist(const int* __restrict__ dst,
                                               int* __restrict__ bcount) {
    __shared__ int h[NCB];
    for (int i = threadIdx.x; i < NCB; i += 256) h[i] = 0;
    __syncthreads();
    int stride = gridDim.x * 256;
    for (int e = blockIdx.x * 256 + threadIdx.x; e < N_EDGES; e += stride)
        atomicAdd(&h[dst[e] >> CBSHIFT], 1);
    __syncthreads();
    for (int i = threadIdx.x; i < NCB; i += 256) {
        int v = h[i];
        if (v) atomicAdd(&bcount[i], v);
    }
}

// ---------------- scan of 196 bucket counts -> bstart, gcur ----------------
__global__ __launch_bounds__(256) void k_bscan(const int* __restrict__ bcount,
                                               int* __restrict__ bstart,
                                               int* __restrict__ gcur) {
    __shared__ int s[256];
    const int t = threadIdx.x;
    int v = (t < NCB) ? bcount[t] : 0;
    s[t] = v;
    __syncthreads();
    for (int off = 1; off < 256; off <<= 1) {
        int x = (t >= off) ? s[t - off] : 0;
        __syncthreads();
        s[t] += x;
        __syncthreads();
    }
    int excl = s[t] - v;
    if (t < NCB) { bstart[t] = excl; gcur[t] = excl; }
    if (t == 255) bstart[NCB] = s[255];
}

// ---------------- pass 1: block-ranked scatter into coarse bucket regions ----------------
__global__ __launch_bounds__(256) void k_p1(const int* __restrict__ src,
                                            const int* __restrict__ dst,
                                            int* __restrict__ gcur,
                                            unsigned int* __restrict__ pairs) {
    __shared__ int hist[NCB], base[NCB], cur[NCB];
    for (int i = threadIdx.x; i < NCB; i += 256) { hist[i] = 0; cur[i] = 0; }
    __syncthreads();
    const int e0 = blockIdx.x * P1_EPB;
    const int e1 = min(e0 + P1_EPB, N_EDGES);
    for (int e = e0 + threadIdx.x; e < e1; e += 256)
        atomicAdd(&hist[dst[e] >> CBSHIFT], 1);
    __syncthreads();
    for (int i = threadIdx.x; i < NCB; i += 256) {
        int c = hist[i];
        base[i] = c ? atomicAdd(&gcur[i], c) : 0;
    }
    __syncthreads();
    for (int e = e0 + threadIdx.x; e < e1; e += 256) {
        int d = dst[e];
        int b = d >> CBSHIFT;
        int r = atomicAdd(&cur[b], 1);
        pairs[base[b] + r] = (unsigned int)src[e] | ((unsigned int)(d & 511) << 17);
    }
}

// ---------------- pass 2: per-bucket sort -> csr_src, row_start, indeg, dinv ----------------
__global__ __launch_bounds__(256) void k_p2(const unsigned int* __restrict__ pairs,
                                            const int* __restrict__ bstart,
                                            int* __restrict__ csr_src,
                                            int* __restrict__ row_start,
                                            int* __restrict__ indeg,
                                            float* __restrict__ dinv) {
    __shared__ int hist[512], sst[512], cur[512], s[256];
    const int b = blockIdx.x;
    const int t = threadIdx.x;
    const int beg = bstart[b];
    const int end = bstart[b + 1];
    for (int i = t; i < 512; i += 256) { hist[i] = 0; cur[i] = 0; }
    __syncthreads();
    for (int i = beg + t; i < end; i += 256)
        atomicAdd(&hist[pairs[i] >> 17], 1);
    __syncthreads();
    int a0 = hist[2 * t], a1 = hist[2 * t + 1];
    int local = a0 + a1;
    s[t] = local;
    __syncthreads();
    for (int off = 1; off < 256; off <<= 1) {
        int x = (t >= off) ? s[t - off] : 0;
        __syncthreads();
        s[t] += x;
        __syncthreads();
    }
    int excl = s[t] - local;
    sst[2 * t] = excl;
    sst[2 * t + 1] = excl + a0;
    __syncthreads();
    for (int i = t; i < 512; i += 256) {
        int node = (b << CBSHIFT) + i;
        if (node < N_NODES) {
            int cnt = hist[i];
            row_start[node] = beg + sst[i];
            indeg[node] = cnt;
            dinv[node] = rsqrtf((float)cnt + 1.0f);
        }
    }
    __syncthreads();
    for (int i = beg + t; i < end; i += 256) {
        unsigned int v = pairs[i];
        int dl = v >> 17;
        int r = atomicAdd(&cur[dl], 1);
        csr_src[beg + sst[dl] + r] = (int)(v & 0x1FFFFu);
    }
}

// ---------------- W prep: fp32 [k][n] -> bf16 transposed [n][k] ----------------
__global__ void k_prepw(const float* __restrict__ W1, const float* __restrict__ W2,
                        unsigned short* __restrict__ WT1, unsigned short* __restrict__ WT2) {
    const float* W = blockIdx.x ? W2 : W1;
    unsigned short* WT = blockIdx.x ? WT2 : WT1;
    for (int i = threadIdx.x; i < 128 * 128; i += blockDim.x) {
        int n = i >> 7, k = i & 127;
        WT[i] = f2bf(W[k * 128 + n]);
    }
}

// ---------------- MFMA GEMM: C[r,:] = bf16( (X[r,:] @ W) * dinv[r] ) ----------------
template<bool SRC_BF16>
__global__ __launch_bounds__(256) void k_gemm_mfma(const void* __restrict__ Xv,
                                                   const unsigned short* __restrict__ WT,
                                                   const float* __restrict__ dinv,
                                                   unsigned short* __restrict__ C,
                                                   int nrows) {
    __shared__ unsigned short As[128][136];
    __shared__ unsigned short Ws[128][136];
    const int tid = threadIdx.x;
    const int R0 = blockIdx.x * 128;

    {
        int r = tid >> 1;
        int h = (tid & 1) * 64;
        int gr = R0 + r;
        if (SRC_BF16) {
            const unsigned short* X = (const unsigned short*)Xv;
            for (int c = 0; c < 64; c += 8) {
                short8 v = {};
                if (gr < nrows) v = *(const short8*)(X + (size_t)gr * NFEAT + h + c);
                *(short8*)(&As[r][h + c]) = v;
            }
        } else {
            const float* X = (const float*)Xv;
            for (int c = 0; c < 64; c += 8) {
                short8 v = {};
                if (gr < nrows) {
                    float4 f0 = *(const float4*)(X + (size_t)gr * NFEAT + h + c);
                    float4 f1 = *(const float4*)(X + (size_t)gr * NFEAT + h + c + 4);
                    v[0] = (short)f2bf(f0.x); v[1] = (short)f2bf(f0.y);
                    v[2] = (short)f2bf(f0.z); v[3] = (short)f2bf(f0.w);
                    v[4] = (short)f2bf(f1.x); v[5] = (short)f2bf(f1.y);
                    v[6] = (short)f2bf(f1.z); v[7] = (short)f2bf(f1.w);
                }
                *(short8*)(&As[r][h + c]) = v;
            }
        }
    }
    {
        int n = tid >> 1;
        int h = (tid & 1) * 64;
        for (int c = 0; c < 64; c += 8)
            *(short8*)(&Ws[n][h + c]) = *(const short8*)(WT + n * 128 + h + c);
    }
    __syncthreads();

    const int wv   = tid >> 6;
    const int lane = tid & 63;
    const int m16  = lane & 15;
    const int quad = lane >> 4;

    f32x4 acc[2][8] = {};
    #pragma unroll
    for (int ks = 0; ks < 4; ++ks) {
        const int k0 = ks * 32 + quad * 8;
        short8 a0 = *(const short8*)(&As[wv * 32 + m16][k0]);
        short8 a1 = *(const short8*)(&As[wv * 32 + 16 + m16][k0]);
        short8 bb[8];
        #pragma unroll
        for (int ct = 0; ct < 8; ++ct)
            bb[ct] = *(const short8*)(&Ws[ct * 16 + m16][k0]);
        #pragma unroll
        for (int ct = 0; ct < 8; ++ct) {
            acc[0][ct] = __builtin_amdgcn_mfma_f32_16x16x32_bf16(a0, bb[ct], acc[0][ct], 0, 0, 0);
            acc[1][ct] = __builtin_amdgcn_mfma_f32_16x16x32_bf16(a1, bb[ct], acc[1][ct], 0, 0, 0);
        }
    }

    #pragma unroll
    for (int t = 0; t < 2; ++t) {
        int rbase = R0 + wv * 32 + t * 16 + quad * 4;
        #pragma unroll
        for (int reg = 0; reg < 4; ++reg) {
            int gr = rbase + reg;
            if (gr < nrows) {
                float dv = dinv[gr];
                #pragma unroll
                for (int ct = 0; ct < 8; ++ct)
                    C[(size_t)gr * NFEAT + ct * 16 + m16] = f2bf(acc[t][ct][reg] * dv);
            }
        }
    }
}

// ---------------- gather layer 1: one node per 16-lane group (4 nodes/wave) ----------------
// each group owns a full 256B row: lane p covers features p*8..p*8+7. No shuffles.
__global__ __launch_bounds__(256) void k_gather1(const unsigned short* __restrict__ xwb,
                                                 const int* __restrict__ csr_src,
                                                 const int* __restrict__ row_start,
                                                 const int* __restrict__ indeg,
                                                 const float* __restrict__ dinv,
                                                 const float* __restrict__ b,
                                                 uint4* __restrict__ outb) {
    long long t = (long long)blockIdx.x * blockDim.x + threadIdx.x;
    int wid = (int)(t >> 6);              // wave id
    const int lane = threadIdx.x & 63;
    const int g = lane >> 4;              // group 0..3
    const int p = lane & 15;              // 16B chunk in row
    int node = wid * 4 + g;
    if (node >= N_NODES) return;
    const uint4* tab = (const uint4*)xwb; // row = 16 uint4
    const int beg = row_start[node];
    const int cnt = indeg[node];
    float acc[8] = {};
    acc8(acc, tab[(size_t)node * 16 + p]);     // self loop
    int j = 0;
    #pragma unroll 1
    for (; j + 4 <= cnt; j += 4) {
        int i0 = csr_src[beg + j + 0];         // same-addr broadcast within group
        int i1 = csr_src[beg + j + 1];
        int i2 = csr_src[beg + j + 2];
        int i3 = csr_src[beg + j + 3];
        uint4 v0 = tab[(size_t)i0 * 16 + p];
        uint4 v1 = tab[(size_t)i1 * 16 + p];
        uint4 v2 = tab[(size_t)i2 * 16 + p];
        uint4 v3 = tab[(size_t)i3 * 16 + p];
        acc8(acc, v0); acc8(acc, v1); acc8(acc, v2); acc8(acc, v3);
    }
    #pragma unroll 1
    for (; j < cnt; ++j)
        acc8(acc, tab[(size_t)csr_src[beg + j] * 16 + p]);
    float dv = dinv[node];
    float4 b0 = *(const float4*)(b + p * 8);
    float4 b1 = *(const float4*)(b + p * 8 + 4);
    float r0 = fmaxf(acc[0] * dv + b0.x, 0.f);
    float r1 = fmaxf(acc[1] * dv + b0.y, 0.f);
    float r2 = fmaxf(acc[2] * dv + b0.z, 0.f);
    float r3 = fmaxf(acc[3] * dv + b0.w, 0.f);
    float r4 = fmaxf(acc[4] * dv + b1.x, 0.f);
    float r5 = fmaxf(acc[5] * dv + b1.y, 0.f);
    float r6 = fmaxf(acc[6] * dv + b1.z, 0.f);
    float r7 = fmaxf(acc[7] * dv + b1.w, 0.f);
    uint4 o;
    o.x = (unsigned int)f2bf(r0) | ((unsigned int)f2bf(r1) << 16);
    o.y = (unsigned int)f2bf(r2) | ((unsigned int)f2bf(r3) << 16);
    o.z = (unsigned int)f2bf(r4) | ((unsigned int)f2bf(r5) << 16);
    o.w = (unsigned int)f2bf(r6) | ((unsigned int)f2bf(r7) << 16);
    outb[(size_t)node * 16 + p] = o;
}

// ---------------- gather layer 2 + fused (h2 . Wlin) + graph segment-sum ----------------
__global__ __launch_bounds__(256) void k_gather2_pool(const unsigned short* __restrict__ xwb,
                                                      const int* __restrict__ csr_src,
                                                      const int* __restrict__ row_start,
                                                      const int* __restrict__ indeg,
                                                      const float* __restrict__ dinv,
                                                      const float* __restrict__ b,
                                                      const float* __restrict__ Wlin,
                                                      const int* __restrict__ batch,
                                                      float* __restrict__ gsum) {
    long long t = (long long)blockIdx.x * blockDim.x + threadIdx.x;
    int wid = (int)(t >> 6);
    const int lane = threadIdx.x & 63;
    const int g = lane >> 4;
    const int p = lane & 15;
    int node = wid * 4 + g;
    if (node >= N_NODES) return;
    const uint4* tab = (const uint4*)xwb;
    const int beg = row_start[node];
    const int cnt = indeg[node];
    float acc[8] = {};
    acc8(acc, tab[(size_t)node * 16 + p]);     // self loop
    int j = 0;
    #pragma unroll 1
    for (; j + 4 <= cnt; j += 4) {
        int i0 = csr_src[beg + j + 0];
        int i1 = csr_src[beg + j + 1];
        int i2 = csr_src[beg + j + 2];
        int i3 = csr_src[beg + j + 3];
        uint4 v0 = tab[(size_t)i0 * 16 + p];
        uint4 v1 = tab[(size_t)i1 * 16 + p];
        uint4 v2 = tab[(size_t)i2 * 16 + p];
        uint4 v3 = tab[(size_t)i3 * 16 + p];
        acc8(acc, v0); acc8(acc, v1); acc8(acc, v2); acc8(acc, v3);
    }
    #pragma unroll 1
    for (; j < cnt; ++j)
        acc8(acc, tab[(size_t)csr_src[beg + j] * 16 + p]);
    // per-lane partial of (h2 . Wlin) over features p*8..p*8+7
    float dv = dinv[node];
    float4 b0 = *(const float4*)(b + p * 8);
    float4 b1 = *(const float4*)(b + p * 8 + 4);
    float4 w0 = *(const float4*)(Wlin + p * 8);
    float4 w1 = *(const float4*)(Wlin + p * 8 + 4);
    float s = (acc[0] * dv + b0.x) * w0.x + (acc[1] * dv + b0.y) * w0.y
            + (acc[2] * dv + b0.z) * w0.z + (acc[3] * dv + b0.w) * w0.w
            + (acc[4] * dv + b1.x) * w1.x + (acc[5] * dv + b1.y) * w1.y
            + (acc[6] * dv + b1.z) * w1.z + (acc[7] * dv + b1.w) * w1.w;
    s += __shfl_xor(s, 1);
    s += __shfl_xor(s, 2);
    s += __shfl_xor(s, 4);
    s += __shfl_xor(s, 8);
    if (p == 0) atomicAdd(&gsum[batch[node]], s);
}

// ---------------- final: counts via binary search on sorted batch ----------------
__global__ void k_final(const float* __restrict__ gsum, const int* __restrict__ batch,
                        const float* __restrict__ blin, float* __restrict__ out) {
    int g = blockIdx.x * blockDim.x + threadIdx.x;
    if (g >= NGRAPHS) return;
    int lo = 0, hi = N_NODES;
    while (lo < hi) { int m = (lo + hi) >> 1; if (batch[m] < g) lo = m + 1; else hi = m; }
    int lb = lo;
    lo = 0; hi = N_NODES;
    int g1 = g + 1;
    while (lo < hi) { int m = (lo + hi) >> 1; if (batch[m] < g1) lo = m + 1; else hi = m; }
    float cnt = (float)(lo - lb);
    out[g] = gsum[g] / fmaxf(cnt, 1.0f) + blin[0];
}

extern "C" void kernel_launch(void* const* d_in, const int* in_sizes, int n_in,
                              void* d_out, int out_size, void* d_ws, size_t ws_size,
                              hipStream_t stream) {
    const float* x    = (const float*)d_in[0];
    const int*   ei   = (const int*)d_in[1];
    const int*   bat  = (const int*)d_in[2];
    const float* W1   = (const float*)d_in[3];
    const float* b1   = (const float*)d_in[4];
    const float* W2   = (const float*)d_in[5];
    const float* b2   = (const float*)d_in[6];
    const float* Wlin = (const float*)d_in[7];
    const float* blin = (const float*)d_in[8];
    float* out = (float*)d_out;

    const int* src = ei;
    const int* dst = ei + N_EDGES;

    // ---- workspace layout ----
    const size_t NF = (size_t)N_NODES * NFEAT;
    unsigned short* bufA = (unsigned short*)d_ws;          // bf16 xw table
    unsigned short* bufB = bufA + NF;                      // bf16 h1 table
    float* dinv    = (float*)(bufB + NF);                  // [N]
    int* row_start = (int*)(dinv + N_NODES);               // [N]
    int* indeg     = row_start + N_NODES;                  // [N]
    int* bstart    = indeg + N_NODES;                      // [NCB+1]
    int* gcur      = bstart + NCB + 1;                     // [NCB]
    int* bcount    = gcur + NCB;                           // [NCB] } zeroed
    float* gsum    = (float*)(bcount + NCB);               // [G]   }
    unsigned short* WT1 = (unsigned short*)(gsum + NGRAPHS);
    unsigned short* WT2 = WT1 + 128 * 128;
    unsigned int* pairs = (unsigned int*)(WT2 + 128 * 128); // [E]
    int* csr_src  = (int*)(pairs + N_EDGES);                // [E]

    const int BS = 256;
    int gemm_blocks = (N_NODES + 127) / 128;
    int p1_blocks   = (N_EDGES + P1_EPB - 1) / P1_EPB;     // 196
    int nwaves      = (N_NODES + 3) / 4;                   // 4 nodes per wave
    int g_blocks    = (int)(((long long)nwaves * 64 + BS - 1) / BS);

    // ---- zero accumulators (bcount,gsum contiguous) ----
    hipMemsetAsync(bcount, 0, NCB * sizeof(int) + NGRAPHS * sizeof(float), stream);

    // ---- two-level counting sort -> CSR (+ indeg, dinv, row_start) ----
    k_bhist<<<128, BS, 0, stream>>>(dst, bcount);
    k_bscan<<<1, BS, 0, stream>>>(bcount, bstart, gcur);
    k_p1<<<p1_blocks, BS, 0, stream>>>(src, dst, gcur, pairs);
    k_p2<<<NCB, BS, 0, stream>>>(pairs, bstart, csr_src, row_start, indeg, dinv);
    k_prepw<<<2, BS, 0, stream>>>(W1, W2, WT1, WT2);

    // ---- layer 1 ----
    k_gemm_mfma<false><<<gemm_blocks, BS, 0, stream>>>(x, WT1, dinv, bufA, N_NODES);
    k_gather1<<<g_blocks, BS, 0, stream>>>(bufA, csr_src, row_start, indeg, dinv, b1, (uint4*)bufB);

    // ---- layer 2 (+ fused pool/linear) ----
    k_gemm_mfma<true><<<gemm_blocks, BS, 0, stream>>>(bufB, WT2, dinv, bufA, N_NODES);
    k_gather2_pool<<<g_blocks, BS, 0, stream>>>(bufA, csr_src, row_start, indeg, dinv, b2,
                                                Wlin, bat, gsum);

    // ---- final ----
    k_final<<<(NGRAPHS + BS - 1) / BS, BS, 0, stream>>>(gsum, bat, blin, out);
}

// Round 8
// 361.991 us; speedup vs baseline: 1.7948x; 1.0358x over previous
//
#include <hip/hip_runtime.h>

#define N_NODES   100000
#define N_EDGES   1600000
#define NFEAT     128
#define NGRAPHS   2048
#define CBSHIFT   9                        // 512 nodes per coarse bucket
#define NCB       ((N_NODES + 511) / 512)  // 196
#define P1_EPB    8192                     // edges per k_p1 block
#define DP_BLOCKS 25
#define DP_NPB    ((N_NODES + DP_BLOCKS - 1) / DP_BLOCKS)   // 4000 nodes/block

typedef __attribute__((ext_vector_type(8))) short short8;   // 8 bf16 = 4 VGPRs
typedef __attribute__((ext_vector_type(4))) float f32x4;

// RNE float -> bf16 (finite inputs)
__device__ __forceinline__ unsigned short f2bf(float f) {
    unsigned int u = __float_as_uint(f);
    u += 0x7FFFu + ((u >> 16) & 1u);
    return (unsigned short)(u >> 16);
}

// accumulate 8 bf16 (packed in uint4) into 8 fp32
__device__ __forceinline__ void acc8(float* acc, uint4 v) {
    acc[0] += __uint_as_float(v.x << 16);
    acc[1] += __uint_as_float(v.x & 0xFFFF0000u);
    acc[2] += __uint_as_float(v.y << 16);
    acc[3] += __uint_as_float(v.y & 0xFFFF0000u);
    acc[4] += __uint_as_float(v.z << 16);
    acc[5] += __uint_as_float(v.z & 0xFFFF0000u);
    acc[6] += __uint_as_float(v.w << 16);
    acc[7] += __uint_as_float(v.w & 0xFFFF0000u);
}

// ---------------- coarse bucket histogram (LDS-aggregated) ----------------
__global__ __launch_bounds__(256) void k_bhist(const int* __restrict__ dst,
                                               int* __restrict__ bcount) {
    __shared__ int h[NCB];
    for (int i = threadIdx.x; i < NCB; i += 256) h[i] = 0;
    __syncthreads();
    int stride = gridDim.x * 256;
    for (int e = blockIdx.x * 256 + threadIdx.x; e < N_EDGES; e += stride)
        atomicAdd(&h[dst[e] >> CBSHIFT], 1);
    __syncthreads();
    for (int i = threadIdx.x; i < NCB; i += 256) {
        int v = h[i];
        if (v) atomicAdd(&bcount[i], v);
    }
}

// ---------------- scan of 196 bucket counts -> bstart, gcur ----------------
__global__ __launch_bounds__(256) void k_bscan(const int* __restrict__ bcount,
                                               int* __restrict__ bstart,
                                               int* __restrict__ gcur) {
    __shared__ int s[256];
    const int t = threadIdx.x;
    int v = (t < NCB) ? bcount[t] : 0;
    s[t] = v;
    __syncthreads();
    for (int off = 1; off < 256; off <<= 1) {
        int x = (t >= off) ? s[t - off] : 0;
        __syncthreads();
        s[t] += x;
        __syncthreads();
    }
    int excl = s[t] - v;
    if (t < NCB) { bstart[t] = excl; gcur[t] = excl; }
    if (t == 255) bstart[NCB] = s[255];
}

// ---------------- pass 1: block-ranked scatter into coarse bucket regions ----------------
__global__ __launch_bounds__(256) void k_p1(const int* __restrict__ src,
                                            const int* __restrict__ dst,
                                            int* __restrict__ gcur,
                                            unsigned int* __restrict__ pairs) {
    __shared__ int hist[NCB], base[NCB], cur[NCB];
    for (int i = threadIdx.x; i < NCB; i += 256) { hist[i] = 0; cur[i] = 0; }
    __syncthreads();
    const int e0 = blockIdx.x * P1_EPB;
    const int e1 = min(e0 + P1_EPB, N_EDGES);
    for (int e = e0 + threadIdx.x; e < e1; e += 256)
        atomicAdd(&hist[dst[e] >> CBSHIFT], 1);
    __syncthreads();
    for (int i = threadIdx.x; i < NCB; i += 256) {
        int c = hist[i];
        base[i] = c ? atomicAdd(&gcur[i], c) : 0;
    }
    __syncthreads();
    for (int e = e0 + threadIdx.x; e < e1; e += 256) {
        int d = dst[e];
        int b = d >> CBSHIFT;
        int r = atomicAdd(&cur[b], 1);
        pairs[base[b] + r] = (unsigned int)src[e] | ((unsigned int)(d & 511) << 17);
    }
}

// ---------------- pass 2: per-bucket sort -> csr_src, row_start, indeg, dinv ----------------
__global__ __launch_bounds__(256) void k_p2(const unsigned int* __restrict__ pairs,
                                            const int* __restrict__ bstart,
                                            int* __restrict__ csr_src,
                                            int* __restrict__ row_start,
                                            int* __restrict__ indeg,
                                            float* __restrict__ dinv) {
    __shared__ int hist[512], sst[512], cur[512], s[256];
    const int b = blockIdx.x;
    const int t = threadIdx.x;
    const int beg = bstart[b];
    const int end = bstart[b + 1];
    for (int i = t; i < 512; i += 256) { hist[i] = 0; cur[i] = 0; }
    __syncthreads();
    for (int i = beg + t; i < end; i += 256)
        atomicAdd(&hist[pairs[i] >> 17], 1);
    __syncthreads();
    int a0 = hist[2 * t], a1 = hist[2 * t + 1];
    int local = a0 + a1;
    s[t] = local;
    __syncthreads();
    for (int off = 1; off < 256; off <<= 1) {
        int x = (t >= off) ? s[t - off] : 0;
        __syncthreads();
        s[t] += x;
        __syncthreads();
    }
    int excl = s[t] - local;
    sst[2 * t] = excl;
    sst[2 * t + 1] = excl + a0;
    __syncthreads();
    for (int i = t; i < 512; i += 256) {
        int node = (b << CBSHIFT) + i;
        if (node < N_NODES) {
            int cnt = hist[i];
            row_start[node] = beg + sst[i];
            indeg[node] = cnt;
            dinv[node] = rsqrtf((float)cnt + 1.0f);
        }
    }
    __syncthreads();
    for (int i = beg + t; i < end; i += 256) {
        unsigned int v = pairs[i];
        int dl = v >> 17;
        int r = atomicAdd(&cur[dl], 1);
        csr_src[beg + sst[dl] + r] = (int)(v & 0x1FFFFu);
    }
}

// ---------------- degree-sort: histogram (64 bins, clamped) ----------------
__global__ __launch_bounds__(256) void k_dhist(const int* __restrict__ indeg,
                                               int* __restrict__ dcount) {
    __shared__ int h[64];
    if (threadIdx.x < 64) h[threadIdx.x] = 0;
    __syncthreads();
    const int i0 = blockIdx.x * DP_NPB;
    const int i1 = min(i0 + DP_NPB, N_NODES);
    for (int i = i0 + threadIdx.x; i < i1; i += 256)
        atomicAdd(&h[min(indeg[i], 63)], 1);
    __syncthreads();
    if (threadIdx.x < 64) {
        int v = h[threadIdx.x];
        if (v) atomicAdd(&dcount[threadIdx.x], v);
    }
}

__global__ __launch_bounds__(64) void k_dscan(const int* __restrict__ dcount,
                                              int* __restrict__ dstart,
                                              int* __restrict__ dcur) {
    __shared__ int s[64];
    const int t = threadIdx.x;
    int v = dcount[t];
    s[t] = v;
    __syncthreads();
    for (int off = 1; off < 64; off <<= 1) {
        int x = (t >= off) ? s[t - off] : 0;
        __syncthreads();
        s[t] += x;
        __syncthreads();
    }
    int excl = s[t] - v;
    dstart[t] = excl;
    dcur[t] = excl;
}

__global__ __launch_bounds__(256) void k_dperm(const int* __restrict__ indeg,
                                               int* __restrict__ dcur,
                                               int* __restrict__ perm) {
    __shared__ int h[64], base[64], cur[64];
    if (threadIdx.x < 64) { h[threadIdx.x] = 0; cur[threadIdx.x] = 0; }
    __syncthreads();
    const int i0 = blockIdx.x * DP_NPB;
    const int i1 = min(i0 + DP_NPB, N_NODES);
    for (int i = i0 + threadIdx.x; i < i1; i += 256)
        atomicAdd(&h[min(indeg[i], 63)], 1);
    __syncthreads();
    if (threadIdx.x < 64) {
        int c = h[threadIdx.x];
        base[threadIdx.x] = c ? atomicAdd(&dcur[threadIdx.x], c) : 0;
    }
    __syncthreads();
    for (int i = i0 + threadIdx.x; i < i1; i += 256) {
        int bin = min(indeg[i], 63);
        int r = atomicAdd(&cur[bin], 1);
        perm[base[bin] + r] = i;
    }
}

// ---------------- W1 prep: fp32 [k][n] -> bf16 transposed [n][k] ----------------
__global__ void k_prepw(const float* __restrict__ W1, unsigned short* __restrict__ WT1) {
    for (int i = threadIdx.x; i < 128 * 128; i += blockDim.x) {
        int n = i >> 7, k = i & 127;
        WT1[i] = f2bf(W1[k * 128 + n]);
    }
}

// ---------------- layer-2 collapse: w2l = W2 @ Wlin, c2 = b2.Wlin + blin ----------------
__global__ void k_prepv(const float* __restrict__ W2, const float* __restrict__ Wlin,
                        const float* __restrict__ b2, const float* __restrict__ blin,
                        float* __restrict__ w2l) {
    int i = threadIdx.x;   // 128 threads
    float s = 0.f;
    for (int j = 0; j < 128; ++j) s += W2[i * 128 + j] * Wlin[j];
    w2l[i] = s;
    if (i == 0) {
        float c = 0.f;
        for (int j = 0; j < 128; ++j) c += b2[j] * Wlin[j];
        w2l[128] = c + blin[0];
    }
}

// ---------------- MFMA GEMM: C[r,:] = bf16( (X[r,:] @ W) * dinv[r] ) ----------------
template<bool SRC_BF16>
__global__ __launch_bounds__(256) void k_gemm_mfma(const void* __restrict__ Xv,
                                                   const unsigned short* __restrict__ WT,
                                                   const float* __restrict__ dinv,
                                                   unsigned short* __restrict__ C,
                                                   int nrows) {
    __shared__ unsigned short As[128][136];
    __shared__ unsigned short Ws[128][136];
    const int tid = threadIdx.x;
    const int R0 = blockIdx.x * 128;

    {
        int r = tid >> 1;
        int h = (tid & 1) * 64;
        int gr = R0 + r;
        if (SRC_BF16) {
            const unsigned short* X = (const unsigned short*)Xv;
            for (int c = 0; c < 64; c += 8) {
                short8 v = {};
                if (gr < nrows) v = *(const short8*)(X + (size_t)gr * NFEAT + h + c);
                *(short8*)(&As[r][h + c]) = v;
            }
        } else {
            const float* X = (const float*)Xv;
            for (int c = 0; c < 64; c += 8) {
                short8 v = {};
                if (gr < nrows) {
                    float4 f0 = *(const float4*)(X + (size_t)gr * NFEAT + h + c);
                    float4 f1 = *(const float4*)(X + (size_t)gr * NFEAT + h + c + 4);
                    v[0] = (short)f2bf(f0.x); v[1] = (short)f2bf(f0.y);
                    v[2] = (short)f2bf(f0.z); v[3] = (short)f2bf(f0.w);
                    v[4] = (short)f2bf(f1.x); v[5] = (short)f2bf(f1.y);
                    v[6] = (short)f2bf(f1.z); v[7] = (short)f2bf(f1.w);
                }
                *(short8*)(&As[r][h + c]) = v;
            }
        }
    }
    {
        int n = tid >> 1;
        int h = (tid & 1) * 64;
        for (int c = 0; c < 64; c += 8)
            *(short8*)(&Ws[n][h + c]) = *(const short8*)(WT + n * 128 + h + c);
    }
    __syncthreads();

    const int wv   = tid >> 6;
    const int lane = tid & 63;
    const int m16  = lane & 15;
    const int quad = lane >> 4;

    f32x4 acc[2][8] = {};
    #pragma unroll
    for (int ks = 0; ks < 4; ++ks) {
        const int k0 = ks * 32 + quad * 8;
        short8 a0 = *(const short8*)(&As[wv * 32 + m16][k0]);
        short8 a1 = *(const short8*)(&As[wv * 32 + 16 + m16][k0]);
        short8 bb[8];
        #pragma unroll
        for (int ct = 0; ct < 8; ++ct)
            bb[ct] = *(const short8*)(&Ws[ct * 16 + m16][k0]);
        #pragma unroll
        for (int ct = 0; ct < 8; ++ct) {
            acc[0][ct] = __builtin_amdgcn_mfma_f32_16x16x32_bf16(a0, bb[ct], acc[0][ct], 0, 0, 0);
            acc[1][ct] = __builtin_amdgcn_mfma_f32_16x16x32_bf16(a1, bb[ct], acc[1][ct], 0, 0, 0);
        }
    }

    #pragma unroll
    for (int t = 0; t < 2; ++t) {
        int rbase = R0 + wv * 32 + t * 16 + quad * 4;
        #pragma unroll
        for (int reg = 0; reg < 4; ++reg) {
            int gr = rbase + reg;
            if (gr < nrows) {
                float dv = dinv[gr];
                #pragma unroll
                for (int ct = 0; ct < 8; ++ct)
                    C[(size_t)gr * NFEAT + ct * 16 + m16] = f2bf(acc[t][ct][reg] * dv);
            }
        }
    }
}

// ---------------- gather layer 1: node per 16-lane group via degree-sorted perm ----------------
// out = bf16( relu(dv*(sum + self) + b1) * dv )   (pre-scaled for layer 2's src use)
__global__ __launch_bounds__(256) void k_gather1(const unsigned short* __restrict__ xwb,
                                                 const int* __restrict__ csr_src,
                                                 const int* __restrict__ row_start,
                                                 const int* __restrict__ indeg,
                                                 const float* __restrict__ dinv,
                                                 const float* __restrict__ b,
                                                 const int* __restrict__ perm,
                                                 uint4* __restrict__ outb) {
    long long t = (long long)blockIdx.x * blockDim.x + threadIdx.x;
    int wid = (int)(t >> 6);
    const int lane = threadIdx.x & 63;
    const int g = lane >> 4;
    const int p = lane & 15;
    int nidx = wid * 4 + g;
    if (nidx >= N_NODES) return;
    int node = perm[nidx];
    const uint4* tab = (const uint4*)xwb;
    const int beg = row_start[node];
    const int cnt = indeg[node];
    float acc[8] = {};
    acc8(acc, tab[(size_t)node * 16 + p]);     // self loop
    int j = 0;
    #pragma unroll 1
    for (; j + 8 <= cnt; j += 8) {
        int i0 = csr_src[beg + j + 0];
        int i1 = csr_src[beg + j + 1];
        int i2 = csr_src[beg + j + 2];
        int i3 = csr_src[beg + j + 3];
        int i4 = csr_src[beg + j + 4];
        int i5 = csr_src[beg + j + 5];
        int i6 = csr_src[beg + j + 6];
        int i7 = csr_src[beg + j + 7];
        uint4 v0 = tab[(size_t)i0 * 16 + p];
        uint4 v1 = tab[(size_t)i1 * 16 + p];
        uint4 v2 = tab[(size_t)i2 * 16 + p];
        uint4 v3 = tab[(size_t)i3 * 16 + p];
        uint4 v4 = tab[(size_t)i4 * 16 + p];
        uint4 v5 = tab[(size_t)i5 * 16 + p];
        uint4 v6 = tab[(size_t)i6 * 16 + p];
        uint4 v7 = tab[(size_t)i7 * 16 + p];
        acc8(acc, v0); acc8(acc, v1); acc8(acc, v2); acc8(acc, v3);
        acc8(acc, v4); acc8(acc, v5); acc8(acc, v6); acc8(acc, v7);
    }
    #pragma unroll 1
    for (; j < cnt; ++j)
        acc8(acc, tab[(size_t)csr_src[beg + j] * 16 + p]);
    float dv = dinv[node];
    float4 b0 = *(const float4*)(b + p * 8);
    float4 b1 = *(const float4*)(b + p * 8 + 4);
    float r0 = fmaxf(acc[0] * dv + b0.x, 0.f) * dv;
    float r1 = fmaxf(acc[1] * dv + b0.y, 0.f) * dv;
    float r2 = fmaxf(acc[2] * dv + b0.z, 0.f) * dv;
    float r3 = fmaxf(acc[3] * dv + b0.w, 0.f) * dv;
    float r4 = fmaxf(acc[4] * dv + b1.x, 0.f) * dv;
    float r5 = fmaxf(acc[5] * dv + b1.y, 0.f) * dv;
    float r6 = fmaxf(acc[6] * dv + b1.z, 0.f) * dv;
    float r7 = fmaxf(acc[7] * dv + b1.w, 0.f) * dv;
    uint4 o;
    o.x = (unsigned int)f2bf(r0) | ((unsigned int)f2bf(r1) << 16);
    o.y = (unsigned int)f2bf(r2) | ((unsigned int)f2bf(r3) << 16);
    o.z = (unsigned int)f2bf(r4) | ((unsigned int)f2bf(r5) << 16);
    o.w = (unsigned int)f2bf(r6) | ((unsigned int)f2bf(r7) << 16);
    outb[(size_t)node * 16 + p] = o;
}

// ---------------- gather layer 2 (on h1s) + dot w2l + graph segment-sum ----------------
// p_node = dv * (sum_{s} h1s[s] + h1s[node]) . w2l ;  gsum[graph] += p_node
__global__ __launch_bounds__(256) void k_gather2_pool(const unsigned short* __restrict__ h1s,
                                                      const int* __restrict__ csr_src,
                                                      const int* __restrict__ row_start,
                                                      const int* __restrict__ indeg,
                                                      const float* __restrict__ dinv,
                                                      const float* __restrict__ w2l,
                                                      const int* __restrict__ perm,
                                                      const int* __restrict__ batch,
                                                      float* __restrict__ gsum) {
    long long t = (long long)blockIdx.x * blockDim.x + threadIdx.x;
    int wid = (int)(t >> 6);
    const int lane = threadIdx.x & 63;
    const int g = lane >> 4;
    const int p = lane & 15;
    int nidx = wid * 4 + g;
    if (nidx >= N_NODES) return;
    int node = perm[nidx];
    const uint4* tab = (const uint4*)h1s;
    const int beg = row_start[node];
    const int cnt = indeg[node];
    float acc[8] = {};
    acc8(acc, tab[(size_t)node * 16 + p]);     // self loop
    int j = 0;
    #pragma unroll 1
    for (; j + 8 <= cnt; j += 8) {
        int i0 = csr_src[beg + j + 0];
        int i1 = csr_src[beg + j + 1];
        int i2 = csr_src[beg + j + 2];
        int i3 = csr_src[beg + j + 3];
        int i4 = csr_src[beg + j + 4];
        int i5 = csr_src[beg + j + 5];
        int i6 = csr_src[beg + j + 6];
        int i7 = csr_src[beg + j + 7];
        uint4 v0 = tab[(size_t)i0 * 16 + p];
        uint4 v1 = tab[(size_t)i1 * 16 + p];
        uint4 v2 = tab[(size_t)i2 * 16 + p];
        uint4 v3 = tab[(size_t)i3 * 16 + p];
        uint4 v4 = tab[(size_t)i4 * 16 + p];
        uint4 v5 = tab[(size_t)i5 * 16 + p];
        uint4 v6 = tab[(size_t)i6 * 16 + p];
        uint4 v7 = tab[(size_t)i7 * 16 + p];
        acc8(acc, v0); acc8(acc, v1); acc8(acc, v2); acc8(acc, v3);
        acc8(acc, v4); acc8(acc, v5); acc8(acc, v6); acc8(acc, v7);
    }
    #pragma unroll 1
    for (; j < cnt; ++j)
        acc8(acc, tab[(size_t)csr_src[beg + j] * 16 + p]);
    float dv = dinv[node];
    float4 w0 = *(const float4*)(w2l + p * 8);
    float4 w1 = *(const float4*)(w2l + p * 8 + 4);
    float s = acc[0] * w0.x + acc[1] * w0.y + acc[2] * w0.z + acc[3] * w0.w
            + acc[4] * w1.x + acc[5] * w1.y + acc[6] * w1.z + acc[7] * w1.w;
    s += __shfl_xor(s, 1);
    s += __shfl_xor(s, 2);
    s += __shfl_xor(s, 4);
    s += __shfl_xor(s, 8);
    if (p == 0) atomicAdd(&gsum[batch[node]], s * dv);
}

// ---------------- final: counts via binary search on sorted batch; +c2 ----------------
__global__ void k_final(const float* __restrict__ gsum, const int* __restrict__ batch,
                        const float* __restrict__ c2, float* __restrict__ out) {
    int g = blockIdx.x * blockDim.x + threadIdx.x;
    if (g >= NGRAPHS) return;
    int lo = 0, hi = N_NODES;
    while (lo < hi) { int m = (lo + hi) >> 1; if (batch[m] < g) lo = m + 1; else hi = m; }
    int lb = lo;
    lo = 0; hi = N_NODES;
    int g1 = g + 1;
    while (lo < hi) { int m = (lo + hi) >> 1; if (batch[m] < g1) lo = m + 1; else hi = m; }
    float cnt = (float)(lo - lb);
    out[g] = gsum[g] / fmaxf(cnt, 1.0f) + c2[0];
}

extern "C" void kernel_launch(void* const* d_in, const int* in_sizes, int n_in,
                              void* d_out, int out_size, void* d_ws, size_t ws_size,
                              hipStream_t stream) {
    const float* x    = (const float*)d_in[0];
    const int*   ei   = (const int*)d_in[1];
    const int*   bat  = (const int*)d_in[2];
    const float* W1   = (const float*)d_in[3];
    const float* b1   = (const float*)d_in[4];
    const float* W2   = (const float*)d_in[5];
    const float* b2   = (const float*)d_in[6];
    const float* Wlin = (const float*)d_in[7];
    const float* blin = (const float*)d_in[8];
    float* out = (float*)d_out;

    const int* src = ei;
    const int* dst = ei + N_EDGES;

    // ---- workspace layout ----
    const size_t NF = (size_t)N_NODES * NFEAT;
    unsigned short* bufA = (unsigned short*)d_ws;          // bf16 xw1 table (dinv-scaled)
    unsigned short* bufB = bufA + NF;                      // bf16 h1s table
    float* dinv    = (float*)(bufB + NF);                  // [N]
    int* row_start = (int*)(dinv + N_NODES);               // [N]
    int* indeg     = row_start + N_NODES;                  // [N]
    int* perm      = indeg + N_NODES;                      // [N]
    int* bstart    = perm + N_NODES;                       // [NCB+1]
    int* gcur      = bstart + NCB + 1;                     // [NCB]
    int* bcount    = gcur + NCB;                           // [NCB]   } zeroed
    float* gsum    = (float*)(bcount + NCB);               // [G]     }
    int* dcount    = (int*)(gsum + NGRAPHS);               // [64]    }
    int* dcur      = dcount + 64;                          // [64]    }
    int* dstart    = dcur + 64;                            // [64]
    unsigned short* WT1 = (unsigned short*)(dstart + 64);  // [16384]
    float* w2l     = (float*)(WT1 + 128 * 128);            // [132] (c2 at [128])
    unsigned int* pairs = (unsigned int*)(w2l + 132);      // [E]
    int* csr_src   = (int*)(pairs + N_EDGES);              // [E]

    const int BS = 256;
    int gemm_blocks = (N_NODES + 127) / 128;
    int p1_blocks   = (N_EDGES + P1_EPB - 1) / P1_EPB;     // 196
    int nwaves      = (N_NODES + 3) / 4;                   // 4 nodes per wave
    int g_blocks    = (int)(((long long)nwaves * 64 + BS - 1) / BS);

    // ---- zero accumulators (bcount,gsum,dcount,dcur contiguous) ----
    hipMemsetAsync(bcount, 0, (NCB + 128) * sizeof(int) + NGRAPHS * sizeof(float), stream);

    // ---- two-level counting sort -> CSR (+ indeg, dinv, row_start) ----
    k_bhist<<<128, BS, 0, stream>>>(dst, bcount);
    k_bscan<<<1, BS, 0, stream>>>(bcount, bstart, gcur);
    k_p1<<<p1_blocks, BS, 0, stream>>>(src, dst, gcur, pairs);
    k_p2<<<NCB, BS, 0, stream>>>(pairs, bstart, csr_src, row_start, indeg, dinv);

    // ---- degree-sorted permutation ----
    k_dhist<<<DP_BLOCKS, BS, 0, stream>>>(indeg, dcount);
    k_dscan<<<1, 64, 0, stream>>>(dcount, dstart, dcur);
    k_dperm<<<DP_BLOCKS, BS, 0, stream>>>(indeg, dcur, perm);

    // ---- weight prep ----
    k_prepw<<<1, BS, 0, stream>>>(W1, WT1);
    k_prepv<<<1, 128, 0, stream>>>(W2, Wlin, b2, blin, w2l);

    // ---- layer 1 ----
    k_gemm_mfma<false><<<gemm_blocks, BS, 0, stream>>>(x, WT1, dinv, bufA, N_NODES);
    k_gather1<<<g_blocks, BS, 0, stream>>>(bufA, csr_src, row_start, indeg, dinv, b1, perm,
                                           (uint4*)bufB);

    // ---- layer 2 + pool + linear (GEMM2 collapsed into w2l) ----
    k_gather2_pool<<<g_blocks, BS, 0, stream>>>(bufB, csr_src, row_start, indeg, dinv, w2l,
                                                perm, bat, gsum);

    // ---- final ----
    k_final<<<(NGRAPHS + BS - 1) / BS, BS, 0, stream>>>(gsum, bat, w2l + 128, out);
}